// Round 13
// baseline (155.876 us; speedup 1.0000x reference)
//
#include <hip/hip_runtime.h>
#include <math.h>

#define N_ 4
#define L_ 2048
#define E_ 512
#define H_ 8
#define D_ 64

// SCALE = 1/sqrt(512) (reference scales by sqrt(embed_size));
// QSCALE = SCALE * log2(e): scores come out of QK^T in log2 domain.
#define QSCALE 0.06375871588055019f

typedef short s16x8 __attribute__((ext_vector_type(8)));
typedef float f32x4 __attribute__((ext_vector_type(4)));
typedef float f32x16 __attribute__((ext_vector_type(16)));
typedef unsigned int u32x4 __attribute__((ext_vector_type(4)));

typedef const __attribute__((address_space(1))) unsigned int ga_u32;
typedef __attribute__((address_space(3))) unsigned int lds_u32;

// async 16B global->LDS (dest = wave-uniform base + lane*16, linear)
__device__ __forceinline__ void gl_lds16(const unsigned short* g, unsigned short* l) {
    __builtin_amdgcn_global_load_lds((ga_u32*)g, (lds_u32*)l, 16, 0, 0);
}
__device__ __forceinline__ float exp2a(float x) {
    float r; asm("v_exp_f32 %0, %1" : "=v"(r) : "v"(x)); return r;
}
__device__ __forceinline__ unsigned int cvtpk(float lo, float hi) {
    unsigned int r; asm("v_cvt_pk_bf16_f32 %0, %1, %2" : "=v"(r) : "v"(lo), "v"(hi)); return r;
}
// v_permlane32_swap_b32 a, b: a<-{a_lo, b_lo}, b<-{a_hi, b_hi} (lane halves)
__device__ __forceinline__ void swap32(unsigned int& a, unsigned int& b) {
    asm volatile("v_permlane32_swap_b32 %0, %1" : "+v"(a), "+v"(b));
}
__device__ __forceinline__ float max3f(float a, float b, float c) {
    return fmaxf(fmaxf(a, b), c);   // clang fuses to v_max3_f32
}
__device__ __forceinline__ unsigned short f2bf(float x) {
    unsigned int u = __builtin_bit_cast(unsigned int, x);
    u = (u + 0x7FFFu + ((u >> 16) & 1u)) >> 16;   // RNE
    return (unsigned short)u;
}
__device__ __forceinline__ float bflo(unsigned int w) {
    return __builtin_bit_cast(float, w << 16);
}
__device__ __forceinline__ float bfhi(unsigned int w) {
    return __builtin_bit_cast(float, w & 0xFFFF0000u);
}
__device__ __forceinline__ s16x8 ld8(const unsigned short* p) {
    return *reinterpret_cast<const s16x8*>(p);
}

// ---------------------------------------------------------------------------
// Kernel 0: split Wo (fp32 512x512) into bf16 hi + bf16 residual lo.
// ---------------------------------------------------------------------------
__global__ __launch_bounds__(256) void wo_split_kernel(
    const float* __restrict__ Wo, unsigned short* __restrict__ Whi,
    unsigned short* __restrict__ Wlo)
{
    const int i = blockIdx.x * 256 + threadIdx.x;
    const float4 w = reinterpret_cast<const float4*>(Wo)[i];
    const unsigned int hxy = cvtpk(w.x, w.y);
    const unsigned int hzw = cvtpk(w.z, w.w);
    const unsigned int lxy = cvtpk(w.x - bflo(hxy), w.y - bfhi(hxy));
    const unsigned int lzw = cvtpk(w.z - bflo(hzw), w.w - bfhi(hzw));
    uint2 hh; hh.x = hxy; hh.y = hzw;
    uint2 ll; ll.x = lxy; ll.y = lzw;
    reinterpret_cast<uint2*>(Whi)[i] = hh;
    reinterpret_cast<uint2*>(Wlo)[i] = ll;
}

// ---------------------------------------------------------------------------
// Kernel 1: per-head QKV projection via bf16 MFMA (round-12 verified).
// ---------------------------------------------------------------------------
__global__ __launch_bounds__(256) void qkv_proj_kernel(
    const float* __restrict__ Q, const float* __restrict__ K, const float* __restrict__ V,
    const float* __restrict__ Wq, const float* __restrict__ Wk, const float* __restrict__ Wv,
    unsigned short* __restrict__ Qp, unsigned short* __restrict__ Kp,
    unsigned short* __restrict__ Vt)
{
    __shared__ __align__(16) unsigned short Xl[4096];     // bf16, swizzled
    __shared__ __align__(16) unsigned short Whl[4096];    // W hi, swizzled
    __shared__ __align__(16) unsigned short Wll[4096];    // W lo, swizzled
    __shared__ __align__(16) unsigned short Yl[64][72];

    const int tid = threadIdx.x;
    const int lt = blockIdx.x;
    const int nh = blockIdx.y;
    const int m  = blockIdx.z;       // 0:Q 1:K 2:V
    const int n = nh >> 3, h = nh & 7;
    const int l0 = lt * 64;

    const float* __restrict__ in = (m == 0) ? Q : (m == 1) ? K : V;
    const float* __restrict__ W  = (m == 0) ? Wq : (m == 1) ? Wk : Wv;

    const int xr = tid >> 2;              // 0..63
    const int xc = (tid & 3) * 16;        // col base
    {
        const float* xs = in + (size_t)(n * L_ + l0 + xr) * E_ + h * D_ + xc;
        float4 a = reinterpret_cast<const float4*>(xs)[0];
        float4 b = reinterpret_cast<const float4*>(xs)[1];
        float4 c = reinterpret_cast<const float4*>(xs)[2];
        float4 d = reinterpret_cast<const float4*>(xs)[3];
        u32x4 w0, w1;
        w0[0] = cvtpk(a.x, a.y); w0[1] = cvtpk(a.z, a.w);
        w0[2] = cvtpk(b.x, b.y); w0[3] = cvtpk(b.z, b.w);
        w1[0] = cvtpk(c.x, c.y); w1[1] = cvtpk(c.z, c.w);
        w1[2] = cvtpk(d.x, d.y); w1[3] = cvtpk(d.z, d.w);
        const int base  = (xr * 64 + xc) ^ ((xr & 7) << 3);
        const int base2 = (xr * 64 + xc + 8) ^ ((xr & 7) << 3);
        *reinterpret_cast<u32x4*>(&Xl[base])  = w0;
        *reinterpret_cast<u32x4*>(&Xl[base2]) = w1;

        const float* wsrc = W + (size_t)xr * D_ + xc;
        float wv[16];
#pragma unroll
        for (int i = 0; i < 4; ++i) {
            const float4 t = reinterpret_cast<const float4*>(wsrc)[i];
            wv[i * 4 + 0] = t.x; wv[i * 4 + 1] = t.y;
            wv[i * 4 + 2] = t.z; wv[i * 4 + 3] = t.w;
        }
        if (m == 0) {
#pragma unroll
            for (int i = 0; i < 16; ++i) wv[i] *= QSCALE;
        }
        u32x4 hi0, hi1, lo0, lo1;
#pragma unroll
        for (int i = 0; i < 4; ++i) {
            const unsigned int hw = cvtpk(wv[2 * i], wv[2 * i + 1]);
            hi0[i] = hw;
            lo0[i] = cvtpk(wv[2 * i] - bflo(hw), wv[2 * i + 1] - bfhi(hw));
        }
#pragma unroll
        for (int i = 0; i < 4; ++i) {
            const unsigned int hw = cvtpk(wv[8 + 2 * i], wv[8 + 2 * i + 1]);
            hi1[i] = hw;
            lo1[i] = cvtpk(wv[8 + 2 * i] - bflo(hw), wv[8 + 2 * i + 1] - bfhi(hw));
        }
        *reinterpret_cast<u32x4*>(&Whl[base])  = hi0;
        *reinterpret_cast<u32x4*>(&Whl[base2]) = hi1;
        *reinterpret_cast<u32x4*>(&Wll[base])  = lo0;
        *reinterpret_cast<u32x4*>(&Wll[base2]) = lo1;
    }
    __syncthreads();

    const int wave = tid >> 6, lane = tid & 63;
    const int ql = lane & 15, g = lane >> 4;
    const int arow = wave * 16 + ql;

    f32x4 acc[4];
#pragma unroll
    for (int t = 0; t < 4; ++t) acc[t] = (f32x4){0.f, 0.f, 0.f, 0.f};

    if (m < 2) {
        s16x8 xf[2];
#pragma unroll
        for (int ks = 0; ks < 2; ++ks)
            xf[ks] = ld8(&Xl[(arow * 64 + ks * 32 + g * 8) ^ ((arow & 7) << 3)]);
#pragma unroll
        for (int t = 0; t < 4; ++t) {
            const int wrow = t * 16 + ql;
#pragma unroll
            for (int ks = 0; ks < 2; ++ks) {
                const s16x8 bh = ld8(&Whl[(wrow * 64 + ks * 32 + g * 8) ^ ((wrow & 7) << 3)]);
                acc[t] = __builtin_amdgcn_mfma_f32_16x16x32_bf16(xf[ks], bh, acc[t], 0, 0, 0);
                const s16x8 bl = ld8(&Wll[(wrow * 64 + ks * 32 + g * 8) ^ ((wrow & 7) << 3)]);
                acc[t] = __builtin_amdgcn_mfma_f32_16x16x32_bf16(xf[ks], bl, acc[t], 0, 0, 0);
            }
        }
    } else {
        s16x8 whf[2], wlf[2];
#pragma unroll
        for (int ks = 0; ks < 2; ++ks) {
            whf[ks] = ld8(&Whl[(arow * 64 + ks * 32 + g * 8) ^ ((arow & 7) << 3)]);
            wlf[ks] = ld8(&Wll[(arow * 64 + ks * 32 + g * 8) ^ ((arow & 7) << 3)]);
        }
#pragma unroll
        for (int t = 0; t < 4; ++t) {
            const int xrow = t * 16 + ql;
#pragma unroll
            for (int ks = 0; ks < 2; ++ks) {
                const s16x8 bx = ld8(&Xl[(xrow * 64 + ks * 32 + g * 8) ^ ((xrow & 7) << 3)]);
                acc[t] = __builtin_amdgcn_mfma_f32_16x16x32_bf16(whf[ks], bx, acc[t], 0, 0, 0);
                acc[t] = __builtin_amdgcn_mfma_f32_16x16x32_bf16(wlf[ks], bx, acc[t], 0, 0, 0);
            }
        }
    }

#pragma unroll
    for (int t = 0; t < 4; ++t)
#pragma unroll
        for (int r = 0; r < 4; ++r)
            Yl[wave * 16 + g * 4 + r][t * 16 + ql] = f2bf(acc[t][r]);
    __syncthreads();

    const int orow = tid >> 2;
    const int oc = (tid & 3) * 16;
    const uint4 v0 = *reinterpret_cast<const uint4*>(&Yl[orow][oc]);
    const uint4 v1 = *reinterpret_cast<const uint4*>(&Yl[orow][oc + 8]);
    unsigned short* dst;
    if (m == 0)      dst = Qp + ((size_t)nh * L_ + l0 + orow) * D_ + oc;
    else if (m == 1) dst = Kp + ((size_t)nh * L_ + l0 + orow) * D_ + oc;
    else             dst = Vt + ((size_t)nh * D_ + orow) * L_ + l0 + oc;
    *reinterpret_cast<uint4*>(dst) = v0;
    *reinterpret_cast<uint4*>(dst + 8) = v1;
}

// ---------------------------------------------------------------------------
// Kernel 2: bf16 MFMA flash attention — DIRECT-LOAD version (this round's
// only structural delta). K/V fragments read straight global->VGPR (K/V are
// L2-resident: 4 heads x 512KB = 2MB per XCD); NO LDS staging, NO per-tile
// barriers -> waves fully independent until the merge, phase drift overlaps
// softmax(waveA) with MFMA(waveB). LDS = dedicated 36KB merge scratch only
// -> 2 blocks/CU x 8 waves = 16 waves/CU (vs 8 before).
// Split-K halves + two-barrier merge kept byte-equivalent to round 10/12.
// ---------------------------------------------------------------------------
__global__ __launch_bounds__(512, 2) void attn_kernel(
    const unsigned short* __restrict__ Qp, const unsigned short* __restrict__ Kp,
    const unsigned short* __restrict__ Vt, unsigned short* __restrict__ AO)
{
    __shared__ __align__(16) float MRG[9216];   // 36KB merge scratch (dedicated)

    const int tid = threadIdx.x;
    const int phys = blockIdx.x;
    const int bid = (phys & 7) * 64 + (phys >> 3);   // bijective: 512 = 8*64
    const int qt = bid & 15;
    const int nh = bid >> 4;          // 4 heads per XCD -> K/V L2-resident
    const int n = nh >> 3, h = nh & 7;
    const int q0 = qt * 128;
    const int wave = tid >> 6;
    const int half = wave >> 2;       // key-range half
    const int w4 = wave & 3;          // wave-in-half: owns q rows w4*32..+31
    const int lane = tid & 63;
    const int l31 = lane & 31;
    const int hh  = lane >> 5;

    const unsigned short* __restrict__ Qb = Qp + (size_t)nh * (L_ * D_);
    const unsigned short* __restrict__ Kb = Kp + (size_t)nh * (L_ * D_);
    const unsigned short* __restrict__ Vb = Vt + (size_t)nh * (D_ * L_);

    const int kbase = half * 1024;    // first key of this half

    // per-lane base pointers:
    // K frag(kt,kv,ks): Kl31 + (kt*64 + kv*32)*64 + ks*16
    const unsigned short* Kl31 = Kb + (size_t)(kbase + l31) * D_ + hh * 8;
    // V frag(kt,dt,kc): Vl31 + dt*32*L + kt*64 + kc*16
    const unsigned short* Vl31 = Vb + (size_t)l31 * L_ + kbase + hh * 8;

    // Q fragments straight to registers: B[k=d][col=q], q=q0+w4*32+l31
    const int qrow = q0 + w4 * 32 + l31;
    s16x8 qfrag[4];
#pragma unroll
    for (int ks = 0; ks < 4; ++ks)
        qfrag[ks] = ld8(Qb + (size_t)qrow * D_ + ks * 16 + hh * 8);

    float m_ = -INFINITY;
    float lsum = 0.f;
    f32x16 ot[2];
    ot[0] = (f32x16)0.f;
    ot[1] = (f32x16)0.f;
    s16x8 pf[4];                      // P frags of tile t-1, live across iters

    const int NT = (L_ / 2) / 64;     // 16 tiles per half

    for (int kt = 0; kt < NT; ++kt) {
        // ---- QK(t): S^T = K·Q^T, K frags direct from global/L2 ----
        f32x16 st[2];
        __builtin_amdgcn_s_setprio(1);
#pragma unroll
        for (int kv = 0; kv < 2; ++kv) {
            st[kv] = (f32x16)0.f;
            const unsigned short* kp = Kl31 + (size_t)(kt * 64 + kv * 32) * D_;
#pragma unroll
            for (int ks = 0; ks < 4; ++ks) {
                const s16x8 kf = ld8(kp + ks * 16);
                st[kv] = __builtin_amdgcn_mfma_f32_32x32x16_bf16(kf, qfrag[ks], st[kv], 0, 0, 0);
            }
        }

        // ---- PV(t-1): V frags direct from global/L2 ----
        if (kt) {
#pragma unroll
            for (int dt = 0; dt < 2; ++dt) {
                const unsigned short* vp = Vl31 + (size_t)dt * 32 * L_ + (kt - 1) * 64;
#pragma unroll
                for (int kc = 0; kc < 4; ++kc) {
                    const s16x8 vf = ld8(vp + kc * 16);
                    ot[dt] = __builtin_amdgcn_mfma_f32_32x32x16_bf16(vf, pf[kc], ot[dt], 0, 0, 0);
                }
            }
        }
        __builtin_amdgcn_s_setprio(0);

        // ---- softmax(t): max3 tree + defer-max rescale + exp + sum + pack ----
        const float t0 = max3f(st[0][0],  st[0][1],  st[0][2]);
        const float t1 = max3f(st[0][3],  st[0][4],  st[0][5]);
        const float t2 = max3f(st[0][6],  st[0][7],  st[0][8]);
        const float t3 = max3f(st[0][9],  st[0][10], st[0][11]);
        const float t4 = max3f(st[0][12], st[0][13], st[0][14]);
        const float t5 = max3f(st[0][15], st[1][0],  st[1][1]);
        const float t6 = max3f(st[1][2],  st[1][3],  st[1][4]);
        const float t7 = max3f(st[1][5],  st[1][6],  st[1][7]);
        const float t8 = max3f(st[1][8],  st[1][9],  st[1][10]);
        const float t9 = max3f(st[1][11], st[1][12], st[1][13]);
        const float ta = fmaxf(st[1][14], st[1][15]);
        const float u0 = max3f(t0, t1, t2);
        const float u1 = max3f(t3, t4, t5);
        const float u2 = max3f(t6, t7, t8);
        const float u3 = fmaxf(t9, ta);
        float tmax = fmaxf(max3f(u0, u1, u2), u3);
        tmax = fmaxf(tmax, __shfl_xor(tmax, 32));

        if (!__all(tmax <= m_ + 8.f)) {       // first tile: m_=-inf -> taken
            const float newm = fmaxf(m_, tmax);
            const float corr = exp2a(m_ - newm);   // 0 on first tile
            lsum *= corr;
            ot[0] *= corr;
            ot[1] *= corr;
            m_ = newm;
        }

        // exp2 in place (<= 2^8 bound via defer-max)
#pragma unroll
        for (int kv = 0; kv < 2; ++kv)
#pragma unroll
            for (int i = 0; i < 16; ++i) st[kv][i] = exp2a(st[kv][i] - m_);

        // tree sum of 32 values (overlapped by the PV MFMAs above)
        {
            float s0 = 0.f, s1 = 0.f, s2 = 0.f, s3 = 0.f;
#pragma unroll
            for (int i = 0; i < 4; ++i) {
                s0 += st[0][i];      s1 += st[0][i + 4];
                s2 += st[0][i + 8];  s3 += st[0][i + 12];
                s0 += st[1][i];      s1 += st[1][i + 4];
                s2 += st[1][i + 8];  s3 += st[1][i + 12];
            }
            float ts = (s0 + s1) + (s2 + s3);
            ts += __shfl_xor(ts, 32);
            lsum += ts;
        }

        // pack P -> PV B-frags (cvt_pk + permlane32_swap)
#pragma unroll
        for (int kv = 0; kv < 2; ++kv) {
            unsigned int A0 = cvtpk(st[kv][0],  st[kv][1]),  B0 = cvtpk(st[kv][2],  st[kv][3]);
            unsigned int A1 = cvtpk(st[kv][4],  st[kv][5]),  B1 = cvtpk(st[kv][6],  st[kv][7]);
            unsigned int A2 = cvtpk(st[kv][8],  st[kv][9]),  B2 = cvtpk(st[kv][10], st[kv][11]);
            unsigned int A3 = cvtpk(st[kv][12], st[kv][13]), B3 = cvtpk(st[kv][14], st[kv][15]);
            swap32(A0, A1); swap32(B0, B1);
            swap32(A2, A3); swap32(B2, B3);
            u32x4 lo; lo[0] = A0; lo[1] = B0; lo[2] = A1; lo[3] = B1;
            u32x4 hi; hi[0] = A2; hi[1] = B2; hi[2] = A3; hi[3] = B3;
            pf[kv * 2 + 0] = __builtin_bit_cast(s16x8, lo);
            pf[kv * 2 + 1] = __builtin_bit_cast(s16x8, hi);
        }
    }

    // ---- per-half pipeline epilogue: final PV (tile NT-1) ----
    __builtin_amdgcn_s_setprio(1);
#pragma unroll
    for (int dt = 0; dt < 2; ++dt) {
        const unsigned short* vp = Vl31 + (size_t)dt * 32 * L_ + (NT - 1) * 64;
#pragma unroll
        for (int kc = 0; kc < 4; ++kc) {
            const s16x8 vf = ld8(vp + kc * 16);
            ot[dt] = __builtin_amdgcn_mfma_f32_32x32x16_bf16(vf, pf[kc], ot[dt], 0, 0, 0);
        }
    }
    __builtin_amdgcn_s_setprio(0);

    // ---- split-K merge via dedicated LDS scratch (two-barrier form) ----
    __syncthreads();
    const int slot = ((w4 << 6) + lane) * 36;      // 36 floats/lane, 16B-aligned
    if (half == 1) {
        *reinterpret_cast<f32x16*>(&MRG[slot])      = ot[0];
        *reinterpret_cast<f32x16*>(&MRG[slot + 16]) = ot[1];
        MRG[slot + 32] = m_;
        MRG[slot + 33] = lsum;
    }
    __syncthreads();
    if (half == 0) {
        const f32x16 ob0 = *reinterpret_cast<const f32x16*>(&MRG[slot]);
        const f32x16 ob1 = *reinterpret_cast<const f32x16*>(&MRG[slot + 16]);
        const float mB = MRG[slot + 32];
        const float lB = MRG[slot + 33];
        const float mm = fmaxf(m_, mB);
        const float sA = exp2a(m_ - mm);
        const float sB = exp2a(mB - mm);
        const float inv = 1.f / (lsum * sA + lB * sB);
        ot[0] = ot[0] * sA + ob0 * sB;
        ot[1] = ot[1] * sA + ob1 * sB;

#pragma unroll
        for (int dt = 0; dt < 2; ++dt) {
#pragma unroll
            for (int r = 0; r < 4; ++r) {
                uint2 o;
                o.x = cvtpk(ot[dt][4 * r + 0] * inv, ot[dt][4 * r + 1] * inv);
                o.y = cvtpk(ot[dt][4 * r + 2] * inv, ot[dt][4 * r + 3] * inv);
                const size_t elem = ((size_t)n * L_ + qrow) * E_ + h * D_ + dt * 32 + r * 8 + hh * 4;
                *reinterpret_cast<uint2*>(AO + elem) = o;
            }
        }
    }
}

// ---------------------------------------------------------------------------
// Kernel 3: output projection via bf16 MFMA with Wo = Whi + Wlo split.
// ---------------------------------------------------------------------------
__global__ __launch_bounds__(256) void out_proj_kernel(
    const unsigned short* __restrict__ AO, const unsigned short* __restrict__ Whi,
    const unsigned short* __restrict__ Wlo, const float* __restrict__ bo,
    float* __restrict__ out)
{
    __shared__ __align__(16) unsigned short Adb[2][4096];
    __shared__ __align__(16) unsigned short Hdb[2][4096];
    __shared__ __align__(16) unsigned short Ldb[2][4096];

    const int tid = threadIdx.x;
    const int bid = blockIdx.x;
    const int mt = bid >> 3, nt = bid & 7;
    const int m0 = mt * 64, n0 = nt * 64;
    const int wave = tid >> 6, lane = tid & 63;
    const int ql = lane & 15, g = lane >> 4;

    const int G0 = wave * 64 + lane;
    const int G1 = G0 + 256;
    const int r0 = G0 >> 3, c0 = (G0 & 7) ^ (r0 & 7);
    const int r1 = G1 >> 3, c1 = (G1 & 7) ^ (r1 & 7);

    const unsigned short* as0 = AO + (size_t)(m0 + r0) * E_ + c0 * 8;
    const unsigned short* as1 = AO + (size_t)(m0 + r1) * E_ + c1 * 8;
    const unsigned short* hs0 = Whi + (size_t)(n0 + r0) * E_ + c0 * 8;
    const unsigned short* hs1 = Whi + (size_t)(n0 + r1) * E_ + c1 * 8;
    const unsigned short* ls0 = Wlo + (size_t)(n0 + r0) * E_ + c0 * 8;
    const unsigned short* ls1 = Wlo + (size_t)(n0 + r1) * E_ + c1 * 8;

    gl_lds16(as0, &Adb[0][wave * 512]);
    gl_lds16(as1, &Adb[0][2048 + wave * 512]);
    gl_lds16(hs0, &Hdb[0][wave * 512]);
    gl_lds16(hs1, &Hdb[0][2048 + wave * 512]);
    gl_lds16(ls0, &Ldb[0][wave * 512]);
    gl_lds16(ls1, &Ldb[0][2048 + wave * 512]);

    float bias[4];
#pragma unroll
    for (int t = 0; t < 4; ++t) bias[t] = bo[n0 + t * 16 + ql];

    f32x4 acc[4];
#pragma unroll
    for (int t = 0; t < 4; ++t) acc[t] = (f32x4){0.f, 0.f, 0.f, 0.f};

    const int arow = wave * 16 + ql;

    for (int kc = 0; kc < 8; ++kc) {
        const int b = kc & 1;
        __syncthreads();
        if (kc + 1 < 8) {
            const int nb = b ^ 1;
            const int ko = (kc + 1) * 64;
            gl_lds16(as0 + ko, &Adb[nb][wave * 512]);
            gl_lds16(as1 + ko, &Adb[nb][2048 + wave * 512]);
            gl_lds16(hs0 + ko, &Hdb[nb][wave * 512]);
            gl_lds16(hs1 + ko, &Hdb[nb][2048 + wave * 512]);
            gl_lds16(ls0 + ko, &Ldb[nb][wave * 512]);
            gl_lds16(ls1 + ko, &Ldb[nb][2048 + wave * 512]);
        }
        const unsigned short* __restrict__ Al = Adb[b];
        const unsigned short* __restrict__ Hl = Hdb[b];
        const unsigned short* __restrict__ Ll = Ldb[b];

        s16x8 af[2];
#pragma unroll
        for (int ks = 0; ks < 2; ++ks)
            af[ks] = ld8(&Al[(arow * 64 + ks * 32 + g * 8) ^ ((arow & 7) << 3)]);

        __builtin_amdgcn_s_setprio(1);
#pragma unroll
        for (int t = 0; t < 4; ++t) {
            const int wrow = t * 16 + ql;
#pragma unroll
            for (int ks = 0; ks < 2; ++ks) {
                const s16x8 bh = ld8(&Hl[(wrow * 64 + ks * 32 + g * 8) ^ ((wrow & 7) << 3)]);
                acc[t] = __builtin_amdgcn_mfma_f32_16x16x32_bf16(af[ks], bh, acc[t], 0, 0, 0);
                const s16x8 bl = ld8(&Ll[(wrow * 64 + ks * 32 + g * 8) ^ ((wrow & 7) << 3)]);
                acc[t] = __builtin_amdgcn_mfma_f32_16x16x32_bf16(af[ks], bl, acc[t], 0, 0, 0);
            }
        }
        __builtin_amdgcn_s_setprio(0);
    }

    // epilogue: D[m = m0+wave*16+g*4+r][n = n0+t*16+ql]
#pragma unroll
    for (int t = 0; t < 4; ++t) {
#pragma unroll
        for (int r = 0; r < 4; ++r) {
            out[(size_t)(m0 + wave * 16 + g * 4 + r) * E_ + n0 + t * 16 + ql] =
                acc[t][r] + bias[t];
        }
    }
}

// ---------------------------------------------------------------------------
extern "C" void kernel_launch(void* const* d_in, const int* in_sizes, int n_in,
                              void* d_out, int out_size, void* d_ws, size_t ws_size,
                              hipStream_t stream)
{
    const float* Q  = (const float*)d_in[0];
    const float* K  = (const float*)d_in[1];
    const float* V  = (const float*)d_in[2];
    const float* Wq = (const float*)d_in[3];
    const float* Wk = (const float*)d_in[4];
    const float* Wv = (const float*)d_in[5];
    const float* Wo = (const float*)d_in[6];
    const float* bo = (const float*)d_in[7];
    float* out = (float*)d_out;

    unsigned short* ws = (unsigned short*)d_ws;
    const size_t SZ = (size_t)N_ * H_ * L_ * D_;   // 4,194,304 elems
    unsigned short* Qp  = ws;
    unsigned short* Kp  = ws + SZ;
    unsigned short* Vt  = ws + 2 * SZ;
    unsigned short* AO  = ws + 3 * SZ;
    unsigned short* Whi = ws + 4 * SZ;
    unsigned short* Wlo = ws + 4 * SZ + 262144;

    qkv_proj_kernel<<<dim3(32, 32, 3), 256, 0, stream>>>(Q, K, V, Wq, Wk, Wv, Qp, Kp, Vt);
    wo_split_kernel<<<256, 256, 0, stream>>>(Wo, Whi, Wlo);
    attn_kernel<<<512, 512, 0, stream>>>(Qp, Kp, Vt, AO);
    out_proj_kernel<<<(8192 / 64) * (E_ / 64), 256, 0, stream>>>(AO, Whi, Wlo, bo, out);
}

// Round 14
// 94.491 us; speedup vs baseline: 1.6496x; 1.6496x over previous
//
#include <hip/hip_runtime.h>
#include <math.h>

#define N_ 4
#define L_ 2048
#define E_ 512
#define H_ 8
#define D_ 64

// SCALE = 1/sqrt(512) (reference scales by sqrt(embed_size));
// QSCALE = SCALE * log2(e): scores come out of QK^T in log2 domain.
#define QSCALE 0.06375871588055019f

typedef short s16x8 __attribute__((ext_vector_type(8)));
typedef float f32x4 __attribute__((ext_vector_type(4)));
typedef float f32x16 __attribute__((ext_vector_type(16)));
typedef unsigned int u32x4 __attribute__((ext_vector_type(4)));

typedef const __attribute__((address_space(1))) unsigned int ga_u32;
typedef __attribute__((address_space(3))) unsigned int lds_u32;

// async 16B global->LDS (dest = wave-uniform base + lane*16, linear)
__device__ __forceinline__ void gl_lds16(const unsigned short* g, unsigned short* l) {
    __builtin_amdgcn_global_load_lds((ga_u32*)g, (lds_u32*)l, 16, 0, 0);
}
__device__ __forceinline__ float exp2a(float x) {
    float r; asm("v_exp_f32 %0, %1" : "=v"(r) : "v"(x)); return r;
}
__device__ __forceinline__ unsigned int cvtpk(float lo, float hi) {
    unsigned int r; asm("v_cvt_pk_bf16_f32 %0, %1, %2" : "=v"(r) : "v"(lo), "v"(hi)); return r;
}
// v_permlane32_swap_b32 a, b: a<-{a_lo, b_lo}, b<-{a_hi, b_hi} (lane halves)
__device__ __forceinline__ void swap32(unsigned int& a, unsigned int& b) {
    asm volatile("v_permlane32_swap_b32 %0, %1" : "+v"(a), "+v"(b));
}
__device__ __forceinline__ float max3f(float a, float b, float c) {
    return fmaxf(fmaxf(a, b), c);   // clang fuses to v_max3_f32
}
__device__ __forceinline__ unsigned short f2bf(float x) {
    unsigned int u = __builtin_bit_cast(unsigned int, x);
    u = (u + 0x7FFFu + ((u >> 16) & 1u)) >> 16;   // RNE
    return (unsigned short)u;
}
__device__ __forceinline__ float bflo(unsigned int w) {
    return __builtin_bit_cast(float, w << 16);
}
__device__ __forceinline__ float bfhi(unsigned int w) {
    return __builtin_bit_cast(float, w & 0xFFFF0000u);
}
__device__ __forceinline__ s16x8 ld8(const unsigned short* p) {
    return *reinterpret_cast<const s16x8*>(p);
}

// ---------------------------------------------------------------------------
// Kernel 0: split Wo (fp32 512x512) into bf16 hi + bf16 residual lo.
// ---------------------------------------------------------------------------
__global__ __launch_bounds__(256) void wo_split_kernel(
    const float* __restrict__ Wo, unsigned short* __restrict__ Whi,
    unsigned short* __restrict__ Wlo)
{
    const int i = blockIdx.x * 256 + threadIdx.x;
    const float4 w = reinterpret_cast<const float4*>(Wo)[i];
    const unsigned int hxy = cvtpk(w.x, w.y);
    const unsigned int hzw = cvtpk(w.z, w.w);
    const unsigned int lxy = cvtpk(w.x - bflo(hxy), w.y - bfhi(hxy));
    const unsigned int lzw = cvtpk(w.z - bflo(hzw), w.w - bfhi(hzw));
    uint2 hh; hh.x = hxy; hh.y = hzw;
    uint2 ll; ll.x = lxy; ll.y = lzw;
    reinterpret_cast<uint2*>(Whi)[i] = hh;
    reinterpret_cast<uint2*>(Wlo)[i] = ll;
}

// ---------------------------------------------------------------------------
// Kernel 1: per-head QKV projection via bf16 MFMA (round-12 verified).
// ---------------------------------------------------------------------------
__global__ __launch_bounds__(256) void qkv_proj_kernel(
    const float* __restrict__ Q, const float* __restrict__ K, const float* __restrict__ V,
    const float* __restrict__ Wq, const float* __restrict__ Wk, const float* __restrict__ Wv,
    unsigned short* __restrict__ Qp, unsigned short* __restrict__ Kp,
    unsigned short* __restrict__ Vt)
{
    __shared__ __align__(16) unsigned short Xl[4096];     // bf16, swizzled
    __shared__ __align__(16) unsigned short Whl[4096];    // W hi, swizzled
    __shared__ __align__(16) unsigned short Wll[4096];    // W lo, swizzled
    __shared__ __align__(16) unsigned short Yl[64][72];

    const int tid = threadIdx.x;
    const int lt = blockIdx.x;
    const int nh = blockIdx.y;
    const int m  = blockIdx.z;       // 0:Q 1:K 2:V
    const int n = nh >> 3, h = nh & 7;
    const int l0 = lt * 64;

    const float* __restrict__ in = (m == 0) ? Q : (m == 1) ? K : V;
    const float* __restrict__ W  = (m == 0) ? Wq : (m == 1) ? Wk : Wv;

    const int xr = tid >> 2;              // 0..63
    const int xc = (tid & 3) * 16;        // col base
    {
        const float* xs = in + (size_t)(n * L_ + l0 + xr) * E_ + h * D_ + xc;
        float4 a = reinterpret_cast<const float4*>(xs)[0];
        float4 b = reinterpret_cast<const float4*>(xs)[1];
        float4 c = reinterpret_cast<const float4*>(xs)[2];
        float4 d = reinterpret_cast<const float4*>(xs)[3];
        u32x4 w0, w1;
        w0[0] = cvtpk(a.x, a.y); w0[1] = cvtpk(a.z, a.w);
        w0[2] = cvtpk(b.x, b.y); w0[3] = cvtpk(b.z, b.w);
        w1[0] = cvtpk(c.x, c.y); w1[1] = cvtpk(c.z, c.w);
        w1[2] = cvtpk(d.x, d.y); w1[3] = cvtpk(d.z, d.w);
        const int base  = (xr * 64 + xc) ^ ((xr & 7) << 3);
        const int base2 = (xr * 64 + xc + 8) ^ ((xr & 7) << 3);
        *reinterpret_cast<u32x4*>(&Xl[base])  = w0;
        *reinterpret_cast<u32x4*>(&Xl[base2]) = w1;

        const float* wsrc = W + (size_t)xr * D_ + xc;
        float wv[16];
#pragma unroll
        for (int i = 0; i < 4; ++i) {
            const float4 t = reinterpret_cast<const float4*>(wsrc)[i];
            wv[i * 4 + 0] = t.x; wv[i * 4 + 1] = t.y;
            wv[i * 4 + 2] = t.z; wv[i * 4 + 3] = t.w;
        }
        if (m == 0) {
#pragma unroll
            for (int i = 0; i < 16; ++i) wv[i] *= QSCALE;
        }
        u32x4 hi0, hi1, lo0, lo1;
#pragma unroll
        for (int i = 0; i < 4; ++i) {
            const unsigned int hw = cvtpk(wv[2 * i], wv[2 * i + 1]);
            hi0[i] = hw;
            lo0[i] = cvtpk(wv[2 * i] - bflo(hw), wv[2 * i + 1] - bfhi(hw));
        }
#pragma unroll
        for (int i = 0; i < 4; ++i) {
            const unsigned int hw = cvtpk(wv[8 + 2 * i], wv[8 + 2 * i + 1]);
            hi1[i] = hw;
            lo1[i] = cvtpk(wv[8 + 2 * i] - bflo(hw), wv[8 + 2 * i + 1] - bfhi(hw));
        }
        *reinterpret_cast<u32x4*>(&Whl[base])  = hi0;
        *reinterpret_cast<u32x4*>(&Whl[base2]) = hi1;
        *reinterpret_cast<u32x4*>(&Wll[base])  = lo0;
        *reinterpret_cast<u32x4*>(&Wll[base2]) = lo1;
    }
    __syncthreads();

    const int wave = tid >> 6, lane = tid & 63;
    const int ql = lane & 15, g = lane >> 4;
    const int arow = wave * 16 + ql;

    f32x4 acc[4];
#pragma unroll
    for (int t = 0; t < 4; ++t) acc[t] = (f32x4){0.f, 0.f, 0.f, 0.f};

    if (m < 2) {
        s16x8 xf[2];
#pragma unroll
        for (int ks = 0; ks < 2; ++ks)
            xf[ks] = ld8(&Xl[(arow * 64 + ks * 32 + g * 8) ^ ((arow & 7) << 3)]);
#pragma unroll
        for (int t = 0; t < 4; ++t) {
            const int wrow = t * 16 + ql;
#pragma unroll
            for (int ks = 0; ks < 2; ++ks) {
                const s16x8 bh = ld8(&Whl[(wrow * 64 + ks * 32 + g * 8) ^ ((wrow & 7) << 3)]);
                acc[t] = __builtin_amdgcn_mfma_f32_16x16x32_bf16(xf[ks], bh, acc[t], 0, 0, 0);
                const s16x8 bl = ld8(&Wll[(wrow * 64 + ks * 32 + g * 8) ^ ((wrow & 7) << 3)]);
                acc[t] = __builtin_amdgcn_mfma_f32_16x16x32_bf16(xf[ks], bl, acc[t], 0, 0, 0);
            }
        }
    } else {
        s16x8 whf[2], wlf[2];
#pragma unroll
        for (int ks = 0; ks < 2; ++ks) {
            whf[ks] = ld8(&Whl[(arow * 64 + ks * 32 + g * 8) ^ ((arow & 7) << 3)]);
            wlf[ks] = ld8(&Wll[(arow * 64 + ks * 32 + g * 8) ^ ((arow & 7) << 3)]);
        }
#pragma unroll
        for (int t = 0; t < 4; ++t) {
            const int xrow = t * 16 + ql;
#pragma unroll
            for (int ks = 0; ks < 2; ++ks) {
                const s16x8 bx = ld8(&Xl[(xrow * 64 + ks * 32 + g * 8) ^ ((xrow & 7) << 3)]);
                acc[t] = __builtin_amdgcn_mfma_f32_16x16x32_bf16(whf[ks], bx, acc[t], 0, 0, 0);
                acc[t] = __builtin_amdgcn_mfma_f32_16x16x32_bf16(wlf[ks], bx, acc[t], 0, 0, 0);
            }
        }
    }

#pragma unroll
    for (int t = 0; t < 4; ++t)
#pragma unroll
        for (int r = 0; r < 4; ++r)
            Yl[wave * 16 + g * 4 + r][t * 16 + ql] = f2bf(acc[t][r]);
    __syncthreads();

    const int orow = tid >> 2;
    const int oc = (tid & 3) * 16;
    const uint4 v0 = *reinterpret_cast<const uint4*>(&Yl[orow][oc]);
    const uint4 v1 = *reinterpret_cast<const uint4*>(&Yl[orow][oc + 8]);
    unsigned short* dst;
    if (m == 0)      dst = Qp + ((size_t)nh * L_ + l0 + orow) * D_ + oc;
    else if (m == 1) dst = Kp + ((size_t)nh * L_ + l0 + orow) * D_ + oc;
    else             dst = Vt + ((size_t)nh * D_ + orow) * L_ + l0 + oc;
    *reinterpret_cast<uint4*>(dst) = v0;
    *reinterpret_cast<uint4*>(dst + 8) = v1;
}

// ---------------------------------------------------------------------------
// Kernel 2: bf16 MFMA flash attention, 32x32x16, in-register P, software
// pipelined, in-block split-K — 64KB LDS variant (2 blocks/CU = 16 waves/CU).
// ROUND-11 BUG POST-MORTEM: the 64KB variant's merge wrote 36KB into ST[1]
// (only 32KB) -> LDS OOB. The V-dbuf sync itself was correct. Fix: merge
// scratch = &ST[0][0] (full 64KB, all dead at that point).
// Per tile t: B1(stage t landed, own-vmcnt drained by syncthreads) ->
// issue K-stage(t+1) into dead K buffer -> QK(t) + PV(t-1) from V[(t-1)&1]
// -> B2(all waves done reading V(t-1)) -> issue V-stage(t+1) into that
// buffer -> softmax(t).  Every gl_lds lands before its first reader because
// __syncthreads drains the issuing wave's vmcnt(0).
// ---------------------------------------------------------------------------
__global__ __launch_bounds__(512, 2) void attn_kernel(
    const unsigned short* __restrict__ Qp, const unsigned short* __restrict__ Kp,
    const unsigned short* __restrict__ Vt, unsigned short* __restrict__ AO)
{
    // [half][buf]: 0-1 = K double-buffer, 2-3 = V double-buffer (64KB total)
    __shared__ __align__(16) unsigned short ST[2][4 * 4096];

    const int tid = threadIdx.x;
    const int phys = blockIdx.x;
    const int bid = (phys & 7) * 64 + (phys >> 3);   // bijective: 512 = 8*64
    const int qt = bid & 15;
    const int nh = bid >> 4;          // 4 heads per XCD -> K/V L2-resident
    const int n = nh >> 3, h = nh & 7;
    const int q0 = qt * 128;
    const int wave = tid >> 6;
    const int half = wave >> 2;       // key-range half
    const int w4 = wave & 3;          // wave-in-half: owns q rows w4*32..+31
    const int lane = tid & 63;
    const int l31 = lane & 31;
    const int hh  = lane >> 5;

    const unsigned short* __restrict__ Qb = Qp + (size_t)nh * (L_ * D_);
    const unsigned short* __restrict__ Kb = Kp + (size_t)nh * (L_ * D_);
    const unsigned short* __restrict__ Vb = Vt + (size_t)nh * (D_ * L_);

    unsigned short* const Kbuf0 = &ST[half][0];
    unsigned short* const Kbuf1 = &ST[half][4096];
    unsigned short* const Vbuf0 = &ST[half][2 * 4096];
    unsigned short* const Vbuf1 = &ST[half][3 * 4096];

    // staging geometry: granule G -> global (row=G>>3, c8=(G&7)^(row&7))
    const int G0 = w4 * 64 + lane;
    const int G1 = G0 + 256;
    const int r0 = G0 >> 3, c0 = (G0 & 7) ^ (r0 & 7);
    const int r1 = G1 >> 3, c1 = (G1 & 7) ^ (r1 & 7);

    const int kbase = half * 1024;    // first key of this half
    const unsigned short* ks0 = Kb + (size_t)(kbase + r0) * 64 + c0 * 8;
    const unsigned short* ks1 = Kb + (size_t)(kbase + r1) * 64 + c1 * 8;
    const unsigned short* vs0 = Vb + (size_t)r0 * L_ + kbase + c0 * 8;
    const unsigned short* vs1 = Vb + (size_t)r1 * L_ + kbase + c1 * 8;

    // prologue: stage kt=0 (K->Kbuf0, V->Vbuf0)
    gl_lds16(ks0, Kbuf0 + w4 * 512);
    gl_lds16(ks1, Kbuf0 + 2048 + w4 * 512);
    gl_lds16(vs0, Vbuf0 + w4 * 512);
    gl_lds16(vs1, Vbuf0 + 2048 + w4 * 512);

    // Q fragments straight to registers: B[k=d][col=q], q=q0+w4*32+l31
    const int qrow = q0 + w4 * 32 + l31;
    s16x8 qfrag[4];
#pragma unroll
    for (int ks = 0; ks < 4; ++ks)
        qfrag[ks] = ld8(Qb + (size_t)qrow * D_ + ks * 16 + hh * 8);

    float m_ = -INFINITY;
    float lsum = 0.f;
    f32x16 ot[2];
    ot[0] = (f32x16)0.f;
    ot[1] = (f32x16)0.f;
    s16x8 pf[4];                      // P frags of tile t-1, live across iters

    const int NT = (L_ / 2) / 64;     // 16 tiles per half

    for (int kt = 0; kt < NT; ++kt) {
        __syncthreads();   // B1: stage(kt) landed; K[kt&1], V[kt&1] valid
        if (kt + 1 < NT) {
            // K buffer (kt+1)&1 is dead (last read: QK(kt-1))
            unsigned short* kn = ((kt + 1) & 1) ? Kbuf1 : Kbuf0;
            gl_lds16(ks0 + (kt + 1) * 4096, kn + w4 * 512);
            gl_lds16(ks1 + (kt + 1) * 4096, kn + 2048 + w4 * 512);
        }
        const unsigned short* __restrict__ Kl = (kt & 1) ? Kbuf1 : Kbuf0;
        // V(t-1) lives in buffer (kt-1)&1 == (kt+1)&1
        unsigned short* const vprev = (kt & 1) ? Vbuf0 : Vbuf1;

        // ---- QK(t): S^T = K·Q^T (log2-domain scores) ----
        f32x16 st[2];
        __builtin_amdgcn_s_setprio(1);
#pragma unroll
        for (int kv = 0; kv < 2; ++kv) {
            st[kv] = (f32x16)0.f;
            const int krow = kv * 32 + l31;
#pragma unroll
            for (int ks = 0; ks < 4; ++ks) {
                const s16x8 kf = ld8(&Kl[(krow * 64 + ks * 16 + hh * 8) ^ ((krow & 7) << 3)]);
                st[kv] = __builtin_amdgcn_mfma_f32_32x32x16_bf16(kf, qfrag[ks], st[kv], 0, 0, 0);
            }
        }

        // ---- PV(t-1) from vprev (in flight during softmax(t)) ----
        if (kt) {
#pragma unroll
            for (int dt = 0; dt < 2; ++dt) {
                const int drow = dt * 32 + l31;
#pragma unroll
                for (int kc = 0; kc < 4; ++kc) {
                    const s16x8 vf = ld8(&vprev[(drow * 64 + kc * 16 + hh * 8) ^ ((drow & 7) << 3)]);
                    ot[dt] = __builtin_amdgcn_mfma_f32_32x32x16_bf16(vf, pf[kc], ot[dt], 0, 0, 0);
                }
            }
        }
        __builtin_amdgcn_s_setprio(0);

        __syncthreads();   // B2: every wave done reading vprev -> reusable
        if (kt + 1 < NT) {
            gl_lds16(vs0 + (kt + 1) * 64, vprev + w4 * 512);
            gl_lds16(vs1 + (kt + 1) * 64, vprev + 2048 + w4 * 512);
        }

        // ---- softmax(t): max3 tree + defer-max rescale + exp + sum + pack ----
        const float t0 = max3f(st[0][0],  st[0][1],  st[0][2]);
        const float t1 = max3f(st[0][3],  st[0][4],  st[0][5]);
        const float t2 = max3f(st[0][6],  st[0][7],  st[0][8]);
        const float t3 = max3f(st[0][9],  st[0][10], st[0][11]);
        const float t4 = max3f(st[0][12], st[0][13], st[0][14]);
        const float t5 = max3f(st[0][15], st[1][0],  st[1][1]);
        const float t6 = max3f(st[1][2],  st[1][3],  st[1][4]);
        const float t7 = max3f(st[1][5],  st[1][6],  st[1][7]);
        const float t8 = max3f(st[1][8],  st[1][9],  st[1][10]);
        const float t9 = max3f(st[1][11], st[1][12], st[1][13]);
        const float ta = fmaxf(st[1][14], st[1][15]);
        const float u0 = max3f(t0, t1, t2);
        const float u1 = max3f(t3, t4, t5);
        const float u2 = max3f(t6, t7, t8);
        const float u3 = fmaxf(t9, ta);
        float tmax = fmaxf(max3f(u0, u1, u2), u3);
        tmax = fmaxf(tmax, __shfl_xor(tmax, 32));

        if (!__all(tmax <= m_ + 8.f)) {       // first tile: m_=-inf -> taken
            const float newm = fmaxf(m_, tmax);
            const float corr = exp2a(m_ - newm);   // 0 on first tile
            lsum *= corr;
            ot[0] *= corr;
            ot[1] *= corr;
            m_ = newm;
        }

        // exp2 in place (<= 2^8 bound via defer-max)
#pragma unroll
        for (int kv = 0; kv < 2; ++kv)
#pragma unroll
            for (int i = 0; i < 16; ++i) st[kv][i] = exp2a(st[kv][i] - m_);

        // tree sum of 32 values (overlapped by the PV MFMAs above)
        {
            float s0 = 0.f, s1 = 0.f, s2 = 0.f, s3 = 0.f;
#pragma unroll
            for (int i = 0; i < 4; ++i) {
                s0 += st[0][i];      s1 += st[0][i + 4];
                s2 += st[0][i + 8];  s3 += st[0][i + 12];
                s0 += st[1][i];      s1 += st[1][i + 4];
                s2 += st[1][i + 8];  s3 += st[1][i + 12];
            }
            float ts = (s0 + s1) + (s2 + s3);
            ts += __shfl_xor(ts, 32);
            lsum += ts;
        }

        // pack P -> PV B-frags (cvt_pk + permlane32_swap)
#pragma unroll
        for (int kv = 0; kv < 2; ++kv) {
            unsigned int A0 = cvtpk(st[kv][0],  st[kv][1]),  B0 = cvtpk(st[kv][2],  st[kv][3]);
            unsigned int A1 = cvtpk(st[kv][4],  st[kv][5]),  B1 = cvtpk(st[kv][6],  st[kv][7]);
            unsigned int A2 = cvtpk(st[kv][8],  st[kv][9]),  B2 = cvtpk(st[kv][10], st[kv][11]);
            unsigned int A3 = cvtpk(st[kv][12], st[kv][13]), B3 = cvtpk(st[kv][14], st[kv][15]);
            swap32(A0, A1); swap32(B0, B1);
            swap32(A2, A3); swap32(B2, B3);
            u32x4 lo; lo[0] = A0; lo[1] = B0; lo[2] = A1; lo[3] = B1;
            u32x4 hi; hi[0] = A2; hi[1] = B2; hi[2] = A3; hi[3] = B3;
            pf[kv * 2 + 0] = __builtin_bit_cast(s16x8, lo);
            pf[kv * 2 + 1] = __builtin_bit_cast(s16x8, hi);
        }
    }

    // ---- per-half pipeline epilogue: final PV from V[(NT-1)&1] ----
    unsigned short* const vlast = ((NT - 1) & 1) ? Vbuf1 : Vbuf0;
    __builtin_amdgcn_s_setprio(1);
#pragma unroll
    for (int dt = 0; dt < 2; ++dt) {
        const int drow = dt * 32 + l31;
#pragma unroll
        for (int kc = 0; kc < 4; ++kc) {
            const s16x8 vf = ld8(&vlast[(drow * 64 + kc * 16 + hh * 8) ^ ((drow & 7) << 3)]);
            ot[dt] = __builtin_amdgcn_mfma_f32_32x32x16_bf16(vf, pf[kc], ot[dt], 0, 0, 0);
        }
    }
    __builtin_amdgcn_s_setprio(0);

    // ---- split-K merge via LDS ----
    // Barrier FIRST: all waves past their last read of ST -> ALL of ST is
    // dead. Merge scratch = &ST[0][0]: 36KB needed <= 64KB available
    // (round-11's bug was writing 36KB into the 32KB ST[1]).
    __syncthreads();
    float* mrg = reinterpret_cast<float*>(&ST[0][0]);
    const int slot = ((w4 << 6) + lane) * 36;      // 36 floats/lane, 16B-aligned
    if (half == 1) {
        *reinterpret_cast<f32x16*>(&mrg[slot])      = ot[0];
        *reinterpret_cast<f32x16*>(&mrg[slot + 16]) = ot[1];
        mrg[slot + 32] = m_;
        mrg[slot + 33] = lsum;
    }
    __syncthreads();
    if (half == 0) {
        const f32x16 ob0 = *reinterpret_cast<const f32x16*>(&mrg[slot]);
        const f32x16 ob1 = *reinterpret_cast<const f32x16*>(&mrg[slot + 16]);
        const float mB = mrg[slot + 32];
        const float lB = mrg[slot + 33];
        const float mm = fmaxf(m_, mB);
        const float sA = exp2a(m_ - mm);
        const float sB = exp2a(mB - mm);
        const float inv = 1.f / (lsum * sA + lB * sB);
        ot[0] = ot[0] * sA + ob0 * sB;
        ot[1] = ot[1] * sA + ob1 * sB;

#pragma unroll
        for (int dt = 0; dt < 2; ++dt) {
#pragma unroll
            for (int r = 0; r < 4; ++r) {
                uint2 o;
                o.x = cvtpk(ot[dt][4 * r + 0] * inv, ot[dt][4 * r + 1] * inv);
                o.y = cvtpk(ot[dt][4 * r + 2] * inv, ot[dt][4 * r + 3] * inv);
                const size_t elem = ((size_t)n * L_ + qrow) * E_ + h * D_ + dt * 32 + r * 8 + hh * 4;
                *reinterpret_cast<uint2*>(AO + elem) = o;
            }
        }
    }
}

// ---------------------------------------------------------------------------
// Kernel 3: output projection via bf16 MFMA with Wo = Whi + Wlo split.
// ---------------------------------------------------------------------------
__global__ __launch_bounds__(256) void out_proj_kernel(
    const unsigned short* __restrict__ AO, const unsigned short* __restrict__ Whi,
    const unsigned short* __restrict__ Wlo, const float* __restrict__ bo,
    float* __restrict__ out)
{
    __shared__ __align__(16) unsigned short Adb[2][4096];
    __shared__ __align__(16) unsigned short Hdb[2][4096];
    __shared__ __align__(16) unsigned short Ldb[2][4096];

    const int tid = threadIdx.x;
    const int bid = blockIdx.x;
    const int mt = bid >> 3, nt = bid & 7;
    const int m0 = mt * 64, n0 = nt * 64;
    const int wave = tid >> 6, lane = tid & 63;
    const int ql = lane & 15, g = lane >> 4;

    const int G0 = wave * 64 + lane;
    const int G1 = G0 + 256;
    const int r0 = G0 >> 3, c0 = (G0 & 7) ^ (r0 & 7);
    const int r1 = G1 >> 3, c1 = (G1 & 7) ^ (r1 & 7);

    const unsigned short* as0 = AO + (size_t)(m0 + r0) * E_ + c0 * 8;
    const unsigned short* as1 = AO + (size_t)(m0 + r1) * E_ + c1 * 8;
    const unsigned short* hs0 = Whi + (size_t)(n0 + r0) * E_ + c0 * 8;
    const unsigned short* hs1 = Whi + (size_t)(n0 + r1) * E_ + c1 * 8;
    const unsigned short* ls0 = Wlo + (size_t)(n0 + r0) * E_ + c0 * 8;
    const unsigned short* ls1 = Wlo + (size_t)(n0 + r1) * E_ + c1 * 8;

    gl_lds16(as0, &Adb[0][wave * 512]);
    gl_lds16(as1, &Adb[0][2048 + wave * 512]);
    gl_lds16(hs0, &Hdb[0][wave * 512]);
    gl_lds16(hs1, &Hdb[0][2048 + wave * 512]);
    gl_lds16(ls0, &Ldb[0][wave * 512]);
    gl_lds16(ls1, &Ldb[0][2048 + wave * 512]);

    float bias[4];
#pragma unroll
    for (int t = 0; t < 4; ++t) bias[t] = bo[n0 + t * 16 + ql];

    f32x4 acc[4];
#pragma unroll
    for (int t = 0; t < 4; ++t) acc[t] = (f32x4){0.f, 0.f, 0.f, 0.f};

    const int arow = wave * 16 + ql;

    for (int kc = 0; kc < 8; ++kc) {
        const int b = kc & 1;
        __syncthreads();
        if (kc + 1 < 8) {
            const int nb = b ^ 1;
            const int ko = (kc + 1) * 64;
            gl_lds16(as0 + ko, &Adb[nb][wave * 512]);
            gl_lds16(as1 + ko, &Adb[nb][2048 + wave * 512]);
            gl_lds16(hs0 + ko, &Hdb[nb][wave * 512]);
            gl_lds16(hs1 + ko, &Hdb[nb][2048 + wave * 512]);
            gl_lds16(ls0 + ko, &Ldb[nb][wave * 512]);
            gl_lds16(ls1 + ko, &Ldb[nb][2048 + wave * 512]);
        }
        const unsigned short* __restrict__ Al = Adb[b];
        const unsigned short* __restrict__ Hl = Hdb[b];
        const unsigned short* __restrict__ Ll = Ldb[b];

        s16x8 af[2];
#pragma unroll
        for (int ks = 0; ks < 2; ++ks)
            af[ks] = ld8(&Al[(arow * 64 + ks * 32 + g * 8) ^ ((arow & 7) << 3)]);

        __builtin_amdgcn_s_setprio(1);
#pragma unroll
        for (int t = 0; t < 4; ++t) {
            const int wrow = t * 16 + ql;
#pragma unroll
            for (int ks = 0; ks < 2; ++ks) {
                const s16x8 bh = ld8(&Hl[(wrow * 64 + ks * 32 + g * 8) ^ ((wrow & 7) << 3)]);
                acc[t] = __builtin_amdgcn_mfma_f32_16x16x32_bf16(af[ks], bh, acc[t], 0, 0, 0);
                const s16x8 bl = ld8(&Ll[(wrow * 64 + ks * 32 + g * 8) ^ ((wrow & 7) << 3)]);
                acc[t] = __builtin_amdgcn_mfma_f32_16x16x32_bf16(af[ks], bl, acc[t], 0, 0, 0);
            }
        }
        __builtin_amdgcn_s_setprio(0);
    }

    // epilogue: D[m = m0+wave*16+g*4+r][n = n0+t*16+ql]
#pragma unroll
    for (int t = 0; t < 4; ++t) {
#pragma unroll
        for (int r = 0; r < 4; ++r) {
            out[(size_t)(m0 + wave * 16 + g * 4 + r) * E_ + n0 + t * 16 + ql] =
                acc[t][r] + bias[t];
        }
    }
}

// ---------------------------------------------------------------------------
extern "C" void kernel_launch(void* const* d_in, const int* in_sizes, int n_in,
                              void* d_out, int out_size, void* d_ws, size_t ws_size,
                              hipStream_t stream)
{
    const float* Q  = (const float*)d_in[0];
    const float* K  = (const float*)d_in[1];
    const float* V  = (const float*)d_in[2];
    const float* Wq = (const float*)d_in[3];
    const float* Wk = (const float*)d_in[4];
    const float* Wv = (const float*)d_in[5];
    const float* Wo = (const float*)d_in[6];
    const float* bo = (const float*)d_in[7];
    float* out = (float*)d_out;

    unsigned short* ws = (unsigned short*)d_ws;
    const size_t SZ = (size_t)N_ * H_ * L_ * D_;   // 4,194,304 elems
    unsigned short* Qp  = ws;
    unsigned short* Kp  = ws + SZ;
    unsigned short* Vt  = ws + 2 * SZ;
    unsigned short* AO  = ws + 3 * SZ;
    unsigned short* Whi = ws + 4 * SZ;
    unsigned short* Wlo = ws + 4 * SZ + 262144;

    qkv_proj_kernel<<<dim3(32, 32, 3), 256, 0, stream>>>(Q, K, V, Wq, Wk, Wv, Qp, Kp, Vt);
    wo_split_kernel<<<256, 256, 0, stream>>>(Wo, Whi, Wlo);
    attn_kernel<<<512, 512, 0, stream>>>(Qp, Kp, Vt, AO);
    out_proj_kernel<<<(8192 / 64) * (E_ / 64), 256, 0, stream>>>(AO, Whi, Wlo, bo, out);
}

// Round 15
// 91.104 us; speedup vs baseline: 1.7110x; 1.0372x over previous
//
#include <hip/hip_runtime.h>
#include <math.h>

#define N_ 4
#define L_ 2048
#define E_ 512
#define H_ 8
#define D_ 64

// SCALE = 1/sqrt(512) (reference scales by sqrt(embed_size));
// QSCALE = SCALE * log2(e): scores come out of QK^T in log2 domain.
#define QSCALE 0.06375871588055019f

typedef short s16x8 __attribute__((ext_vector_type(8)));
typedef float f32x4 __attribute__((ext_vector_type(4)));
typedef float f32x16 __attribute__((ext_vector_type(16)));
typedef unsigned int u32x4 __attribute__((ext_vector_type(4)));

typedef const __attribute__((address_space(1))) unsigned int ga_u32;
typedef __attribute__((address_space(3))) unsigned int lds_u32;

// async 16B global->LDS (dest = wave-uniform base + lane*16, linear)
__device__ __forceinline__ void gl_lds16(const unsigned short* g, unsigned short* l) {
    __builtin_amdgcn_global_load_lds((ga_u32*)g, (lds_u32*)l, 16, 0, 0);
}
__device__ __forceinline__ float exp2a(float x) {
    float r; asm("v_exp_f32 %0, %1" : "=v"(r) : "v"(x)); return r;
}
__device__ __forceinline__ unsigned int cvtpk(float lo, float hi) {
    unsigned int r; asm("v_cvt_pk_bf16_f32 %0, %1, %2" : "=v"(r) : "v"(lo), "v"(hi)); return r;
}
// v_permlane32_swap_b32 a, b: a<-{a_lo, b_lo}, b<-{a_hi, b_hi} (lane halves)
__device__ __forceinline__ void swap32(unsigned int& a, unsigned int& b) {
    asm volatile("v_permlane32_swap_b32 %0, %1" : "+v"(a), "+v"(b));
}
__device__ __forceinline__ float max3f(float a, float b, float c) {
    return fmaxf(fmaxf(a, b), c);   // clang fuses to v_max3_f32
}
__device__ __forceinline__ unsigned short f2bf(float x) {
    unsigned int u = __builtin_bit_cast(unsigned int, x);
    u = (u + 0x7FFFu + ((u >> 16) & 1u)) >> 16;   // RNE
    return (unsigned short)u;
}
__device__ __forceinline__ float bflo(unsigned int w) {
    return __builtin_bit_cast(float, w << 16);
}
__device__ __forceinline__ float bfhi(unsigned int w) {
    return __builtin_bit_cast(float, w & 0xFFFF0000u);
}
__device__ __forceinline__ s16x8 ld8(const unsigned short* p) {
    return *reinterpret_cast<const s16x8*>(p);
}

// ---------------------------------------------------------------------------
// Kernel 0: split Wo (fp32 512x512) into bf16 hi + bf16 residual lo.
// ---------------------------------------------------------------------------
__global__ __launch_bounds__(256) void wo_split_kernel(
    const float* __restrict__ Wo, unsigned short* __restrict__ Whi,
    unsigned short* __restrict__ Wlo)
{
    const int i = blockIdx.x * 256 + threadIdx.x;
    const float4 w = reinterpret_cast<const float4*>(Wo)[i];
    const unsigned int hxy = cvtpk(w.x, w.y);
    const unsigned int hzw = cvtpk(w.z, w.w);
    const unsigned int lxy = cvtpk(w.x - bflo(hxy), w.y - bfhi(hxy));
    const unsigned int lzw = cvtpk(w.z - bflo(hzw), w.w - bfhi(hzw));
    uint2 hh; hh.x = hxy; hh.y = hzw;
    uint2 ll; ll.x = lxy; ll.y = lzw;
    reinterpret_cast<uint2*>(Whi)[i] = hh;
    reinterpret_cast<uint2*>(Wlo)[i] = ll;
}

// ---------------------------------------------------------------------------
// Kernel 1: per-head QKV projection via bf16 MFMA (round-12 verified).
// ---------------------------------------------------------------------------
__global__ __launch_bounds__(256) void qkv_proj_kernel(
    const float* __restrict__ Q, const float* __restrict__ K, const float* __restrict__ V,
    const float* __restrict__ Wq, const float* __restrict__ Wk, const float* __restrict__ Wv,
    unsigned short* __restrict__ Qp, unsigned short* __restrict__ Kp,
    unsigned short* __restrict__ Vt)
{
    __shared__ __align__(16) unsigned short Xl[4096];     // bf16, swizzled
    __shared__ __align__(16) unsigned short Whl[4096];    // W hi, swizzled
    __shared__ __align__(16) unsigned short Wll[4096];    // W lo, swizzled
    __shared__ __align__(16) unsigned short Yl[64][72];

    const int tid = threadIdx.x;
    const int lt = blockIdx.x;
    const int nh = blockIdx.y;
    const int m  = blockIdx.z;       // 0:Q 1:K 2:V
    const int n = nh >> 3, h = nh & 7;
    const int l0 = lt * 64;

    const float* __restrict__ in = (m == 0) ? Q : (m == 1) ? K : V;
    const float* __restrict__ W  = (m == 0) ? Wq : (m == 1) ? Wk : Wv;

    const int xr = tid >> 2;              // 0..63
    const int xc = (tid & 3) * 16;        // col base
    {
        const float* xs = in + (size_t)(n * L_ + l0 + xr) * E_ + h * D_ + xc;
        float4 a = reinterpret_cast<const float4*>(xs)[0];
        float4 b = reinterpret_cast<const float4*>(xs)[1];
        float4 c = reinterpret_cast<const float4*>(xs)[2];
        float4 d = reinterpret_cast<const float4*>(xs)[3];
        u32x4 w0, w1;
        w0[0] = cvtpk(a.x, a.y); w0[1] = cvtpk(a.z, a.w);
        w0[2] = cvtpk(b.x, b.y); w0[3] = cvtpk(b.z, b.w);
        w1[0] = cvtpk(c.x, c.y); w1[1] = cvtpk(c.z, c.w);
        w1[2] = cvtpk(d.x, d.y); w1[3] = cvtpk(d.z, d.w);
        const int base  = (xr * 64 + xc) ^ ((xr & 7) << 3);
        const int base2 = (xr * 64 + xc + 8) ^ ((xr & 7) << 3);
        *reinterpret_cast<u32x4*>(&Xl[base])  = w0;
        *reinterpret_cast<u32x4*>(&Xl[base2]) = w1;

        const float* wsrc = W + (size_t)xr * D_ + xc;
        float wv[16];
#pragma unroll
        for (int i = 0; i < 4; ++i) {
            const float4 t = reinterpret_cast<const float4*>(wsrc)[i];
            wv[i * 4 + 0] = t.x; wv[i * 4 + 1] = t.y;
            wv[i * 4 + 2] = t.z; wv[i * 4 + 3] = t.w;
        }
        if (m == 0) {
#pragma unroll
            for (int i = 0; i < 16; ++i) wv[i] *= QSCALE;
        }
        u32x4 hi0, hi1, lo0, lo1;
#pragma unroll
        for (int i = 0; i < 4; ++i) {
            const unsigned int hw = cvtpk(wv[2 * i], wv[2 * i + 1]);
            hi0[i] = hw;
            lo0[i] = cvtpk(wv[2 * i] - bflo(hw), wv[2 * i + 1] - bfhi(hw));
        }
#pragma unroll
        for (int i = 0; i < 4; ++i) {
            const unsigned int hw = cvtpk(wv[8 + 2 * i], wv[8 + 2 * i + 1]);
            hi1[i] = hw;
            lo1[i] = cvtpk(wv[8 + 2 * i] - bflo(hw), wv[8 + 2 * i + 1] - bfhi(hw));
        }
        *reinterpret_cast<u32x4*>(&Whl[base])  = hi0;
        *reinterpret_cast<u32x4*>(&Whl[base2]) = hi1;
        *reinterpret_cast<u32x4*>(&Wll[base])  = lo0;
        *reinterpret_cast<u32x4*>(&Wll[base2]) = lo1;
    }
    __syncthreads();

    const int wave = tid >> 6, lane = tid & 63;
    const int ql = lane & 15, g = lane >> 4;
    const int arow = wave * 16 + ql;

    f32x4 acc[4];
#pragma unroll
    for (int t = 0; t < 4; ++t) acc[t] = (f32x4){0.f, 0.f, 0.f, 0.f};

    if (m < 2) {
        s16x8 xf[2];
#pragma unroll
        for (int ks = 0; ks < 2; ++ks)
            xf[ks] = ld8(&Xl[(arow * 64 + ks * 32 + g * 8) ^ ((arow & 7) << 3)]);
#pragma unroll
        for (int t = 0; t < 4; ++t) {
            const int wrow = t * 16 + ql;
#pragma unroll
            for (int ks = 0; ks < 2; ++ks) {
                const s16x8 bh = ld8(&Whl[(wrow * 64 + ks * 32 + g * 8) ^ ((wrow & 7) << 3)]);
                acc[t] = __builtin_amdgcn_mfma_f32_16x16x32_bf16(xf[ks], bh, acc[t], 0, 0, 0);
                const s16x8 bl = ld8(&Wll[(wrow * 64 + ks * 32 + g * 8) ^ ((wrow & 7) << 3)]);
                acc[t] = __builtin_amdgcn_mfma_f32_16x16x32_bf16(xf[ks], bl, acc[t], 0, 0, 0);
            }
        }
    } else {
        s16x8 whf[2], wlf[2];
#pragma unroll
        for (int ks = 0; ks < 2; ++ks) {
            whf[ks] = ld8(&Whl[(arow * 64 + ks * 32 + g * 8) ^ ((arow & 7) << 3)]);
            wlf[ks] = ld8(&Wll[(arow * 64 + ks * 32 + g * 8) ^ ((arow & 7) << 3)]);
        }
#pragma unroll
        for (int t = 0; t < 4; ++t) {
            const int xrow = t * 16 + ql;
#pragma unroll
            for (int ks = 0; ks < 2; ++ks) {
                const s16x8 bx = ld8(&Xl[(xrow * 64 + ks * 32 + g * 8) ^ ((xrow & 7) << 3)]);
                acc[t] = __builtin_amdgcn_mfma_f32_16x16x32_bf16(whf[ks], bx, acc[t], 0, 0, 0);
                acc[t] = __builtin_amdgcn_mfma_f32_16x16x32_bf16(wlf[ks], bx, acc[t], 0, 0, 0);
            }
        }
    }

#pragma unroll
    for (int t = 0; t < 4; ++t)
#pragma unroll
        for (int r = 0; r < 4; ++r)
            Yl[wave * 16 + g * 4 + r][t * 16 + ql] = f2bf(acc[t][r]);
    __syncthreads();

    const int orow = tid >> 2;
    const int oc = (tid & 3) * 16;
    const uint4 v0 = *reinterpret_cast<const uint4*>(&Yl[orow][oc]);
    const uint4 v1 = *reinterpret_cast<const uint4*>(&Yl[orow][oc + 8]);
    unsigned short* dst;
    if (m == 0)      dst = Qp + ((size_t)nh * L_ + l0 + orow) * D_ + oc;
    else if (m == 1) dst = Kp + ((size_t)nh * L_ + l0 + orow) * D_ + oc;
    else             dst = Vt + ((size_t)nh * D_ + orow) * L_ + l0 + oc;
    *reinterpret_cast<uint4*>(dst) = v0;
    *reinterpret_cast<uint4*>(dst + 8) = v1;
}

// ---------------------------------------------------------------------------
// Kernel 2: bf16 MFMA flash attention, 32x32x16, in-block split-K, 64KB LDS.
// THIS ROUND: compute loop subtiled at 32 keys to cut registers below the
// 128 combined VGPR+AGPR occupancy cliff (round-14: 72+64=136 -> 3 waves/SIMD
// -> only 1 block/CU). st: f32x16 x1 (-16 AGPR), pf: 2 frags (-8 VGPR)
// -> ~112 total -> 4 waves/SIMD -> 2 blocks/CU = 16 waves/CU.
// Staging cadence UNCHANGED from round-14 (64-key K/V tiles, dbuf, B1/B2 at
// even subtiles). Liveness: K(T-1) last read QK(2T-1) < B1(2T); V(T-1) last
// read PV(2T-1) < B2(2T). Merge: ST[0] scratch (36KB <= 64KB), barrier-first.
// ---------------------------------------------------------------------------
__global__ __launch_bounds__(512, 2) void attn_kernel(
    const unsigned short* __restrict__ Qp, const unsigned short* __restrict__ Kp,
    const unsigned short* __restrict__ Vt, unsigned short* __restrict__ AO)
{
    // [half][buf]: 0-1 = K double-buffer, 2-3 = V double-buffer (64KB total)
    __shared__ __align__(16) unsigned short ST[2][4 * 4096];

    const int tid = threadIdx.x;
    const int phys = blockIdx.x;
    const int bid = (phys & 7) * 64 + (phys >> 3);   // bijective: 512 = 8*64
    const int qt = bid & 15;
    const int nh = bid >> 4;          // 4 heads per XCD -> K/V L2-resident
    const int n = nh >> 3, h = nh & 7;
    const int q0 = qt * 128;
    const int wave = tid >> 6;
    const int half = wave >> 2;       // key-range half
    const int w4 = wave & 3;          // wave-in-half: owns q rows w4*32..+31
    const int lane = tid & 63;
    const int l31 = lane & 31;
    const int hh  = lane >> 5;

    const unsigned short* __restrict__ Qb = Qp + (size_t)nh * (L_ * D_);
    const unsigned short* __restrict__ Kb = Kp + (size_t)nh * (L_ * D_);
    const unsigned short* __restrict__ Vb = Vt + (size_t)nh * (D_ * L_);

    unsigned short* const Kbuf0 = &ST[half][0];
    unsigned short* const Kbuf1 = &ST[half][4096];
    unsigned short* const Vbuf0 = &ST[half][2 * 4096];
    unsigned short* const Vbuf1 = &ST[half][3 * 4096];

    // staging geometry: granule G -> global (row=G>>3, c8=(G&7)^(row&7))
    const int G0 = w4 * 64 + lane;
    const int G1 = G0 + 256;
    const int r0 = G0 >> 3, c0 = (G0 & 7) ^ (r0 & 7);
    const int r1 = G1 >> 3, c1 = (G1 & 7) ^ (r1 & 7);

    const int kbase = half * 1024;    // first key of this half
    const unsigned short* ks0 = Kb + (size_t)(kbase + r0) * 64 + c0 * 8;
    const unsigned short* ks1 = Kb + (size_t)(kbase + r1) * 64 + c1 * 8;
    const unsigned short* vs0 = Vb + (size_t)r0 * L_ + kbase + c0 * 8;
    const unsigned short* vs1 = Vb + (size_t)r1 * L_ + kbase + c1 * 8;

    // prologue: stage staged-tile T=0 (K->Kbuf0, V->Vbuf0)
    gl_lds16(ks0, Kbuf0 + w4 * 512);
    gl_lds16(ks1, Kbuf0 + 2048 + w4 * 512);
    gl_lds16(vs0, Vbuf0 + w4 * 512);
    gl_lds16(vs1, Vbuf0 + 2048 + w4 * 512);

    // Q fragments straight to registers: B[k=d][col=q], q=q0+w4*32+l31
    const int qrow = q0 + w4 * 32 + l31;
    s16x8 qfrag[4];
#pragma unroll
    for (int ks = 0; ks < 4; ++ks)
        qfrag[ks] = ld8(Qb + (size_t)qrow * D_ + ks * 16 + hh * 8);

    float m_ = -INFINITY;
    float lsum = 0.f;
    f32x16 ot[2];
    ot[0] = (f32x16)0.f;
    ot[1] = (f32x16)0.f;
    s16x8 pf[2];                      // P frags of subtile s-1 (32 keys)

    const int NS = (L_ / 2) / 32;     // 32 subtiles per half (16 staged tiles)

    for (int s = 0; s < NS; ++s) {
        const int T = s >> 1;
        if ((s & 1) == 0) {
            __syncthreads();   // B1: staged tile T fully landed
            if (T + 1 < 16) {
                // K buffer (T+1)&1 dead since QK(2T-1)
                unsigned short* kn = ((T + 1) & 1) ? Kbuf1 : Kbuf0;
                gl_lds16(ks0 + (T + 1) * 4096, kn + w4 * 512);
                gl_lds16(ks1 + (T + 1) * 4096, kn + 2048 + w4 * 512);
            }
        }
        const unsigned short* __restrict__ Kl = (T & 1) ? Kbuf1 : Kbuf0;
        const int kro = (s & 1) * 32;     // key-half within staged tile

        // ---- QK(s): S^T = K·Q^T over 32 keys (log2-domain scores) ----
        f32x16 st = (f32x16)0.f;
        __builtin_amdgcn_s_setprio(1);
        {
            const int krow = kro + l31;
            const int swz = (l31 & 7) << 3;   // (krow&7)==(l31&7): kro%32==0
#pragma unroll
            for (int ks = 0; ks < 4; ++ks) {
                const s16x8 kf = ld8(&Kl[(krow * 64 + ks * 16 + hh * 8) ^ swz]);
                st = __builtin_amdgcn_mfma_f32_32x32x16_bf16(kf, qfrag[ks], st, 0, 0, 0);
            }
        }

        // ---- PV(s-1): 32 keys from V buffer ((s-1)>>1)&1, half (s-1)&1 ----
        if (s) {
            const unsigned short* __restrict__ Vl = (((s - 1) >> 1) & 1) ? Vbuf1 : Vbuf0;
            const int vco = ((s - 1) & 1) * 32;
#pragma unroll
            for (int dt = 0; dt < 2; ++dt) {
                const int drow = dt * 32 + l31;
                const int swz = (l31 & 7) << 3;
#pragma unroll
                for (int kc = 0; kc < 2; ++kc) {
                    const s16x8 vf = ld8(&Vl[(drow * 64 + vco + kc * 16 + hh * 8) ^ swz]);
                    ot[dt] = __builtin_amdgcn_mfma_f32_32x32x16_bf16(vf, pf[kc], ot[dt], 0, 0, 0);
                }
            }
        }
        __builtin_amdgcn_s_setprio(0);

        if ((s & 1) == 0) {
            __syncthreads();   // B2: V(T-1) fully read by everyone
            if (T + 1 < 16) {
                unsigned short* vn = ((T + 1) & 1) ? Vbuf1 : Vbuf0;
                gl_lds16(vs0 + (T + 1) * 64, vn + w4 * 512);
                gl_lds16(vs1 + (T + 1) * 64, vn + 2048 + w4 * 512);
            }
        }

        // ---- softmax(s): 16 scores/lane ----
        const float t0 = max3f(st[0],  st[1],  st[2]);
        const float t1 = max3f(st[3],  st[4],  st[5]);
        const float t2 = max3f(st[6],  st[7],  st[8]);
        const float t3 = max3f(st[9],  st[10], st[11]);
        const float t4 = max3f(st[12], st[13], st[14]);
        const float u0 = max3f(t0, t1, t2);
        const float u1 = max3f(t3, t4, st[15]);
        float tmax = fmaxf(u0, u1);
        tmax = fmaxf(tmax, __shfl_xor(tmax, 32));

        if (!__all(tmax <= m_ + 8.f)) {       // first subtile: m_=-inf -> taken
            const float newm = fmaxf(m_, tmax);
            const float corr = exp2a(m_ - newm);   // 0 on first subtile
            lsum *= corr;
            ot[0] *= corr;
            ot[1] *= corr;
            m_ = newm;
        }

        // exp2 in place (<= 2^8 bound via defer-max)
#pragma unroll
        for (int i = 0; i < 16; ++i) st[i] = exp2a(st[i] - m_);

        // tree sum (overlapped by the PV MFMAs above)
        {
            float s0 = 0.f, s1 = 0.f, s2 = 0.f, s3 = 0.f;
#pragma unroll
            for (int i = 0; i < 4; ++i) {
                s0 += st[i];      s1 += st[i + 4];
                s2 += st[i + 8];  s3 += st[i + 12];
            }
            float ts = (s0 + s1) + (s2 + s3);
            ts += __shfl_xor(ts, 32);
            lsum += ts;
        }

        // pack P -> PV B-frags (cvt_pk + permlane32_swap)
        {
            unsigned int A0 = cvtpk(st[0],  st[1]),  B0 = cvtpk(st[2],  st[3]);
            unsigned int A1 = cvtpk(st[4],  st[5]),  B1 = cvtpk(st[6],  st[7]);
            unsigned int A2 = cvtpk(st[8],  st[9]),  B2 = cvtpk(st[10], st[11]);
            unsigned int A3 = cvtpk(st[12], st[13]), B3 = cvtpk(st[14], st[15]);
            swap32(A0, A1); swap32(B0, B1);
            swap32(A2, A3); swap32(B2, B3);
            u32x4 lo; lo[0] = A0; lo[1] = B0; lo[2] = A1; lo[3] = B1;
            u32x4 hi; hi[0] = A2; hi[1] = B2; hi[2] = A3; hi[3] = B3;
            pf[0] = __builtin_bit_cast(s16x8, lo);
            pf[1] = __builtin_bit_cast(s16x8, hi);
        }
    }

    // ---- epilogue: final PV (subtile NS-1) ----
    {
        const unsigned short* __restrict__ Vl = (((NS - 1) >> 1) & 1) ? Vbuf1 : Vbuf0;
        const int vco = ((NS - 1) & 1) * 32;
        __builtin_amdgcn_s_setprio(1);
#pragma unroll
        for (int dt = 0; dt < 2; ++dt) {
            const int drow = dt * 32 + l31;
            const int swz = (l31 & 7) << 3;
#pragma unroll
            for (int kc = 0; kc < 2; ++kc) {
                const s16x8 vf = ld8(&Vl[(drow * 64 + vco + kc * 16 + hh * 8) ^ swz]);
                ot[dt] = __builtin_amdgcn_mfma_f32_32x32x16_bf16(vf, pf[kc], ot[dt], 0, 0, 0);
            }
        }
        __builtin_amdgcn_s_setprio(0);
    }

    // ---- split-K merge via LDS (ST[0] scratch, barrier-first) ----
    __syncthreads();
    float* mrg = reinterpret_cast<float*>(&ST[0][0]);
    const int slot = ((w4 << 6) + lane) * 36;      // 36 floats/lane, 16B-aligned
    if (half == 1) {
        *reinterpret_cast<f32x16*>(&mrg[slot])      = ot[0];
        *reinterpret_cast<f32x16*>(&mrg[slot + 16]) = ot[1];
        mrg[slot + 32] = m_;
        mrg[slot + 33] = lsum;
    }
    __syncthreads();
    if (half == 0) {
        const f32x16 ob0 = *reinterpret_cast<const f32x16*>(&mrg[slot]);
        const f32x16 ob1 = *reinterpret_cast<const f32x16*>(&mrg[slot + 16]);
        const float mB = mrg[slot + 32];
        const float lB = mrg[slot + 33];
        const float mm = fmaxf(m_, mB);
        const float sA = exp2a(m_ - mm);
        const float sB = exp2a(mB - mm);
        const float inv = 1.f / (lsum * sA + lB * sB);
        ot[0] = ot[0] * sA + ob0 * sB;
        ot[1] = ot[1] * sA + ob1 * sB;

#pragma unroll
        for (int dt = 0; dt < 2; ++dt) {
#pragma unroll
            for (int r = 0; r < 4; ++r) {
                uint2 o;
                o.x = cvtpk(ot[dt][4 * r + 0] * inv, ot[dt][4 * r + 1] * inv);
                o.y = cvtpk(ot[dt][4 * r + 2] * inv, ot[dt][4 * r + 3] * inv);
                const size_t elem = ((size_t)n * L_ + qrow) * E_ + h * D_ + dt * 32 + r * 8 + hh * 4;
                *reinterpret_cast<uint2*>(AO + elem) = o;
            }
        }
    }
}

// ---------------------------------------------------------------------------
// Kernel 3: output projection via bf16 MFMA with Wo = Whi + Wlo split.
// ---------------------------------------------------------------------------
__global__ __launch_bounds__(256) void out_proj_kernel(
    const unsigned short* __restrict__ AO, const unsigned short* __restrict__ Whi,
    const unsigned short* __restrict__ Wlo, const float* __restrict__ bo,
    float* __restrict__ out)
{
    __shared__ __align__(16) unsigned short Adb[2][4096];
    __shared__ __align__(16) unsigned short Hdb[2][4096];
    __shared__ __align__(16) unsigned short Ldb[2][4096];

    const int tid = threadIdx.x;
    const int bid = blockIdx.x;
    const int mt = bid >> 3, nt = bid & 7;
    const int m0 = mt * 64, n0 = nt * 64;
    const int wave = tid >> 6, lane = tid & 63;
    const int ql = lane & 15, g = lane >> 4;

    const int G0 = wave * 64 + lane;
    const int G1 = G0 + 256;
    const int r0 = G0 >> 3, c0 = (G0 & 7) ^ (r0 & 7);
    const int r1 = G1 >> 3, c1 = (G1 & 7) ^ (r1 & 7);

    const unsigned short* as0 = AO + (size_t)(m0 + r0) * E_ + c0 * 8;
    const unsigned short* as1 = AO + (size_t)(m0 + r1) * E_ + c1 * 8;
    const unsigned short* hs0 = Whi + (size_t)(n0 + r0) * E_ + c0 * 8;
    const unsigned short* hs1 = Whi + (size_t)(n0 + r1) * E_ + c1 * 8;
    const unsigned short* ls0 = Wlo + (size_t)(n0 + r0) * E_ + c0 * 8;
    const unsigned short* ls1 = Wlo + (size_t)(n0 + r1) * E_ + c1 * 8;

    gl_lds16(as0, &Adb[0][wave * 512]);
    gl_lds16(as1, &Adb[0][2048 + wave * 512]);
    gl_lds16(hs0, &Hdb[0][wave * 512]);
    gl_lds16(hs1, &Hdb[0][2048 + wave * 512]);
    gl_lds16(ls0, &Ldb[0][wave * 512]);
    gl_lds16(ls1, &Ldb[0][2048 + wave * 512]);

    float bias[4];
#pragma unroll
    for (int t = 0; t < 4; ++t) bias[t] = bo[n0 + t * 16 + ql];

    f32x4 acc[4];
#pragma unroll
    for (int t = 0; t < 4; ++t) acc[t] = (f32x4){0.f, 0.f, 0.f, 0.f};

    const int arow = wave * 16 + ql;

    for (int kc = 0; kc < 8; ++kc) {
        const int b = kc & 1;
        __syncthreads();
        if (kc + 1 < 8) {
            const int nb = b ^ 1;
            const int ko = (kc + 1) * 64;
            gl_lds16(as0 + ko, &Adb[nb][wave * 512]);
            gl_lds16(as1 + ko, &Adb[nb][2048 + wave * 512]);
            gl_lds16(hs0 + ko, &Hdb[nb][wave * 512]);
            gl_lds16(hs1 + ko, &Hdb[nb][2048 + wave * 512]);
            gl_lds16(ls0 + ko, &Ldb[nb][wave * 512]);
            gl_lds16(ls1 + ko, &Ldb[nb][2048 + wave * 512]);
        }
        const unsigned short* __restrict__ Al = Adb[b];
        const unsigned short* __restrict__ Hl = Hdb[b];
        const unsigned short* __restrict__ Ll = Ldb[b];

        s16x8 af[2];
#pragma unroll
        for (int ks = 0; ks < 2; ++ks)
            af[ks] = ld8(&Al[(arow * 64 + ks * 32 + g * 8) ^ ((arow & 7) << 3)]);

        __builtin_amdgcn_s_setprio(1);
#pragma unroll
        for (int t = 0; t < 4; ++t) {
            const int wrow = t * 16 + ql;
#pragma unroll
            for (int ks = 0; ks < 2; ++ks) {
                const s16x8 bh = ld8(&Hl[(wrow * 64 + ks * 32 + g * 8) ^ ((wrow & 7) << 3)]);
                acc[t] = __builtin_amdgcn_mfma_f32_16x16x32_bf16(af[ks], bh, acc[t], 0, 0, 0);
                const s16x8 bl = ld8(&Ll[(wrow * 64 + ks * 32 + g * 8) ^ ((wrow & 7) << 3)]);
                acc[t] = __builtin_amdgcn_mfma_f32_16x16x32_bf16(af[ks], bl, acc[t], 0, 0, 0);
            }
        }
        __builtin_amdgcn_s_setprio(0);
    }

    // epilogue: D[m = m0+wave*16+g*4+r][n = n0+t*16+ql]
#pragma unroll
    for (int t = 0; t < 4; ++t) {
#pragma unroll
        for (int r = 0; r < 4; ++r) {
            out[(size_t)(m0 + wave * 16 + g * 4 + r) * E_ + n0 + t * 16 + ql] =
                acc[t][r] + bias[t];
        }
    }
}

// ---------------------------------------------------------------------------
extern "C" void kernel_launch(void* const* d_in, const int* in_sizes, int n_in,
                              void* d_out, int out_size, void* d_ws, size_t ws_size,
                              hipStream_t stream)
{
    const float* Q  = (const float*)d_in[0];
    const float* K  = (const float*)d_in[1];
    const float* V  = (const float*)d_in[2];
    const float* Wq = (const float*)d_in[3];
    const float* Wk = (const float*)d_in[4];
    const float* Wv = (const float*)d_in[5];
    const float* Wo = (const float*)d_in[6];
    const float* bo = (const float*)d_in[7];
    float* out = (float*)d_out;

    unsigned short* ws = (unsigned short*)d_ws;
    const size_t SZ = (size_t)N_ * H_ * L_ * D_;   // 4,194,304 elems
    unsigned short* Qp  = ws;
    unsigned short* Kp  = ws + SZ;
    unsigned short* Vt  = ws + 2 * SZ;
    unsigned short* AO  = ws + 3 * SZ;
    unsigned short* Whi = ws + 4 * SZ;
    unsigned short* Wlo = ws + 4 * SZ + 262144;

    qkv_proj_kernel<<<dim3(32, 32, 3), 256, 0, stream>>>(Q, K, V, Wq, Wk, Wv, Qp, Kp, Vt);
    wo_split_kernel<<<256, 256, 0, stream>>>(Wo, Whi, Wlo);
    attn_kernel<<<512, 512, 0, stream>>>(Qp, Kp, Vt, AO);
    out_proj_kernel<<<(8192 / 64) * (E_ / 64), 256, 0, stream>>>(AO, Whi, Wlo, bo, out);
}

// Round 16
// 89.091 us; speedup vs baseline: 1.7496x; 1.0226x over previous
//
#include <hip/hip_runtime.h>
#include <math.h>

#define N_ 4
#define L_ 2048
#define E_ 512
#define H_ 8
#define D_ 64

// SCALE = 1/sqrt(512) (reference scales by sqrt(embed_size));
// QSCALE = SCALE * log2(e): scores come out of QK^T in log2 domain.
#define QSCALE 0.06375871588055019f

typedef short s16x8 __attribute__((ext_vector_type(8)));
typedef float f32x4 __attribute__((ext_vector_type(4)));
typedef float f32x16 __attribute__((ext_vector_type(16)));
typedef unsigned int u32x4 __attribute__((ext_vector_type(4)));

typedef const __attribute__((address_space(1))) unsigned int ga_u32;
typedef __attribute__((address_space(3))) unsigned int lds_u32;

// async 16B global->LDS (dest = wave-uniform base + lane*16, linear)
__device__ __forceinline__ void gl_lds16(const unsigned short* g, unsigned short* l) {
    __builtin_amdgcn_global_load_lds((ga_u32*)g, (lds_u32*)l, 16, 0, 0);
}
__device__ __forceinline__ float exp2a(float x) {
    float r; asm("v_exp_f32 %0, %1" : "=v"(r) : "v"(x)); return r;
}
__device__ __forceinline__ unsigned int cvtpk(float lo, float hi) {
    unsigned int r; asm("v_cvt_pk_bf16_f32 %0, %1, %2" : "=v"(r) : "v"(lo), "v"(hi)); return r;
}
// v_permlane32_swap_b32 a, b: a<-{a_lo, b_lo}, b<-{a_hi, b_hi} (lane halves)
__device__ __forceinline__ void swap32(unsigned int& a, unsigned int& b) {
    asm volatile("v_permlane32_swap_b32 %0, %1" : "+v"(a), "+v"(b));
}
__device__ __forceinline__ float max3f(float a, float b, float c) {
    return fmaxf(fmaxf(a, b), c);   // clang fuses to v_max3_f32
}
__device__ __forceinline__ unsigned short f2bf(float x) {
    unsigned int u = __builtin_bit_cast(unsigned int, x);
    u = (u + 0x7FFFu + ((u >> 16) & 1u)) >> 16;   // RNE
    return (unsigned short)u;
}
__device__ __forceinline__ float bflo(unsigned int w) {
    return __builtin_bit_cast(float, w << 16);
}
__device__ __forceinline__ float bfhi(unsigned int w) {
    return __builtin_bit_cast(float, w & 0xFFFF0000u);
}
__device__ __forceinline__ s16x8 ld8(const unsigned short* p) {
    return *reinterpret_cast<const s16x8*>(p);
}

// ---------------------------------------------------------------------------
// Kernel 1: per-head QKV projection via bf16 MFMA (round-12 verified).
// z-slice m==3 (first 256 blocks): wo_split folded in (saves a dispatch).
// ---------------------------------------------------------------------------
__global__ __launch_bounds__(256) void qkv_proj_kernel(
    const float* __restrict__ Q, const float* __restrict__ K, const float* __restrict__ V,
    const float* __restrict__ Wq, const float* __restrict__ Wk, const float* __restrict__ Wv,
    const float* __restrict__ Wo,
    unsigned short* __restrict__ Qp, unsigned short* __restrict__ Kp,
    unsigned short* __restrict__ Vt,
    unsigned short* __restrict__ Whi, unsigned short* __restrict__ Wlo)
{
    __shared__ __align__(16) unsigned short Xl[4096];     // bf16, swizzled
    __shared__ __align__(16) unsigned short Whl[4096];    // W hi, swizzled
    __shared__ __align__(16) unsigned short Wll[4096];    // W lo, swizzled
    __shared__ __align__(16) unsigned short Yl[64][72];

    const int tid = threadIdx.x;
    const int lt = blockIdx.x;
    const int nh = blockIdx.y;
    const int m  = blockIdx.z;       // 0:Q 1:K 2:V 3:wo_split
    const int n = nh >> 3, h = nh & 7;
    const int l0 = lt * 64;

    if (m == 3) {
        const int bidx = lt + nh * 32;
        if (bidx < 256) {
            const int i = bidx * 256 + tid;
            const float4 w = reinterpret_cast<const float4*>(Wo)[i];
            const unsigned int hxy = cvtpk(w.x, w.y);
            const unsigned int hzw = cvtpk(w.z, w.w);
            const unsigned int lxy = cvtpk(w.x - bflo(hxy), w.y - bfhi(hxy));
            const unsigned int lzw = cvtpk(w.z - bflo(hzw), w.w - bfhi(hzw));
            uint2 hh2; hh2.x = hxy; hh2.y = hzw;
            uint2 ll2; ll2.x = lxy; ll2.y = lzw;
            reinterpret_cast<uint2*>(Whi)[i] = hh2;
            reinterpret_cast<uint2*>(Wlo)[i] = ll2;
        }
        return;
    }

    const float* __restrict__ in = (m == 0) ? Q : (m == 1) ? K : V;
    const float* __restrict__ W  = (m == 0) ? Wq : (m == 1) ? Wk : Wv;

    const int xr = tid >> 2;              // 0..63
    const int xc = (tid & 3) * 16;        // col base
    {
        const float* xs = in + (size_t)(n * L_ + l0 + xr) * E_ + h * D_ + xc;
        float4 a = reinterpret_cast<const float4*>(xs)[0];
        float4 b = reinterpret_cast<const float4*>(xs)[1];
        float4 c = reinterpret_cast<const float4*>(xs)[2];
        float4 d = reinterpret_cast<const float4*>(xs)[3];
        u32x4 w0, w1;
        w0[0] = cvtpk(a.x, a.y); w0[1] = cvtpk(a.z, a.w);
        w0[2] = cvtpk(b.x, b.y); w0[3] = cvtpk(b.z, b.w);
        w1[0] = cvtpk(c.x, c.y); w1[1] = cvtpk(c.z, c.w);
        w1[2] = cvtpk(d.x, d.y); w1[3] = cvtpk(d.z, d.w);
        const int base  = (xr * 64 + xc) ^ ((xr & 7) << 3);
        const int base2 = (xr * 64 + xc + 8) ^ ((xr & 7) << 3);
        *reinterpret_cast<u32x4*>(&Xl[base])  = w0;
        *reinterpret_cast<u32x4*>(&Xl[base2]) = w1;

        const float* wsrc = W + (size_t)xr * D_ + xc;
        float wv[16];
#pragma unroll
        for (int i = 0; i < 4; ++i) {
            const float4 t = reinterpret_cast<const float4*>(wsrc)[i];
            wv[i * 4 + 0] = t.x; wv[i * 4 + 1] = t.y;
            wv[i * 4 + 2] = t.z; wv[i * 4 + 3] = t.w;
        }
        if (m == 0) {
#pragma unroll
            for (int i = 0; i < 16; ++i) wv[i] *= QSCALE;
        }
        u32x4 hi0, hi1, lo0, lo1;
#pragma unroll
        for (int i = 0; i < 4; ++i) {
            const unsigned int hw = cvtpk(wv[2 * i], wv[2 * i + 1]);
            hi0[i] = hw;
            lo0[i] = cvtpk(wv[2 * i] - bflo(hw), wv[2 * i + 1] - bfhi(hw));
        }
#pragma unroll
        for (int i = 0; i < 4; ++i) {
            const unsigned int hw = cvtpk(wv[8 + 2 * i], wv[8 + 2 * i + 1]);
            hi1[i] = hw;
            lo1[i] = cvtpk(wv[8 + 2 * i] - bflo(hw), wv[8 + 2 * i + 1] - bfhi(hw));
        }
        *reinterpret_cast<u32x4*>(&Whl[base])  = hi0;
        *reinterpret_cast<u32x4*>(&Whl[base2]) = hi1;
        *reinterpret_cast<u32x4*>(&Wll[base])  = lo0;
        *reinterpret_cast<u32x4*>(&Wll[base2]) = lo1;
    }
    __syncthreads();

    const int wave = tid >> 6, lane = tid & 63;
    const int ql = lane & 15, g = lane >> 4;
    const int arow = wave * 16 + ql;

    f32x4 acc[4];
#pragma unroll
    for (int t = 0; t < 4; ++t) acc[t] = (f32x4){0.f, 0.f, 0.f, 0.f};

    if (m < 2) {
        s16x8 xf[2];
#pragma unroll
        for (int ks = 0; ks < 2; ++ks)
            xf[ks] = ld8(&Xl[(arow * 64 + ks * 32 + g * 8) ^ ((arow & 7) << 3)]);
#pragma unroll
        for (int t = 0; t < 4; ++t) {
            const int wrow = t * 16 + ql;
#pragma unroll
            for (int ks = 0; ks < 2; ++ks) {
                const s16x8 bh = ld8(&Whl[(wrow * 64 + ks * 32 + g * 8) ^ ((wrow & 7) << 3)]);
                acc[t] = __builtin_amdgcn_mfma_f32_16x16x32_bf16(xf[ks], bh, acc[t], 0, 0, 0);
                const s16x8 bl = ld8(&Wll[(wrow * 64 + ks * 32 + g * 8) ^ ((wrow & 7) << 3)]);
                acc[t] = __builtin_amdgcn_mfma_f32_16x16x32_bf16(xf[ks], bl, acc[t], 0, 0, 0);
            }
        }
    } else {
        s16x8 whf[2], wlf[2];
#pragma unroll
        for (int ks = 0; ks < 2; ++ks) {
            whf[ks] = ld8(&Whl[(arow * 64 + ks * 32 + g * 8) ^ ((arow & 7) << 3)]);
            wlf[ks] = ld8(&Wll[(arow * 64 + ks * 32 + g * 8) ^ ((arow & 7) << 3)]);
        }
#pragma unroll
        for (int t = 0; t < 4; ++t) {
            const int xrow = t * 16 + ql;
#pragma unroll
            for (int ks = 0; ks < 2; ++ks) {
                const s16x8 bx = ld8(&Xl[(xrow * 64 + ks * 32 + g * 8) ^ ((xrow & 7) << 3)]);
                acc[t] = __builtin_amdgcn_mfma_f32_16x16x32_bf16(whf[ks], bx, acc[t], 0, 0, 0);
                acc[t] = __builtin_amdgcn_mfma_f32_16x16x32_bf16(wlf[ks], bx, acc[t], 0, 0, 0);
            }
        }
    }

#pragma unroll
    for (int t = 0; t < 4; ++t)
#pragma unroll
        for (int r = 0; r < 4; ++r)
            Yl[wave * 16 + g * 4 + r][t * 16 + ql] = f2bf(acc[t][r]);
    __syncthreads();

    const int orow = tid >> 2;
    const int oc = (tid & 3) * 16;
    const uint4 v0 = *reinterpret_cast<const uint4*>(&Yl[orow][oc]);
    const uint4 v1 = *reinterpret_cast<const uint4*>(&Yl[orow][oc + 8]);
    unsigned short* dst;
    if (m == 0)      dst = Qp + ((size_t)nh * L_ + l0 + orow) * D_ + oc;
    else if (m == 1) dst = Kp + ((size_t)nh * L_ + l0 + orow) * D_ + oc;
    else             dst = Vt + ((size_t)nh * D_ + orow) * L_ + l0 + oc;
    *reinterpret_cast<uint4*>(dst) = v0;
    *reinterpret_cast<uint4*>(dst + 8) = v1;
}

// ---------------------------------------------------------------------------
// Kernel 2: bf16 MFMA flash attention, 32x32x16, in-block split-K, 64KB LDS,
// 32-key compute subtiles (round-15 verified base).
// THIS ROUND: ones-MFMA lsum re-added (round-5/6-verified pattern) — the
// sum tree + shfl leave the softmax critical path; the per-q key-sum rides
// the underutilized matrix pipe (issued deferred, with PV(s-1)).
// Register budget: VGPR 56+4(onesf)=60, AGPR 48+16(lsacc)=64 -> 124 <= 128
// -> still 4 waves/SIMD, 2 blocks/CU.
// ---------------------------------------------------------------------------
__global__ __launch_bounds__(512, 2) void attn_kernel(
    const unsigned short* __restrict__ Qp, const unsigned short* __restrict__ Kp,
    const unsigned short* __restrict__ Vt, unsigned short* __restrict__ AO)
{
    // [half][buf]: 0-1 = K double-buffer, 2-3 = V double-buffer (64KB total)
    __shared__ __align__(16) unsigned short ST[2][4 * 4096];

    const int tid = threadIdx.x;
    const int phys = blockIdx.x;
    const int bid = (phys & 7) * 64 + (phys >> 3);   // bijective: 512 = 8*64
    const int qt = bid & 15;
    const int nh = bid >> 4;          // 4 heads per XCD -> K/V L2-resident
    const int n = nh >> 3, h = nh & 7;
    const int q0 = qt * 128;
    const int wave = tid >> 6;
    const int half = wave >> 2;       // key-range half
    const int w4 = wave & 3;          // wave-in-half: owns q rows w4*32..+31
    const int lane = tid & 63;
    const int l31 = lane & 31;
    const int hh  = lane >> 5;

    const unsigned short* __restrict__ Qb = Qp + (size_t)nh * (L_ * D_);
    const unsigned short* __restrict__ Kb = Kp + (size_t)nh * (L_ * D_);
    const unsigned short* __restrict__ Vb = Vt + (size_t)nh * (D_ * L_);

    unsigned short* const Kbuf0 = &ST[half][0];
    unsigned short* const Kbuf1 = &ST[half][4096];
    unsigned short* const Vbuf0 = &ST[half][2 * 4096];
    unsigned short* const Vbuf1 = &ST[half][3 * 4096];

    // staging geometry: granule G -> global (row=G>>3, c8=(G&7)^(row&7))
    const int G0 = w4 * 64 + lane;
    const int G1 = G0 + 256;
    const int r0 = G0 >> 3, c0 = (G0 & 7) ^ (r0 & 7);
    const int r1 = G1 >> 3, c1 = (G1 & 7) ^ (r1 & 7);

    const int kbase = half * 1024;    // first key of this half
    const unsigned short* ks0 = Kb + (size_t)(kbase + r0) * 64 + c0 * 8;
    const unsigned short* ks1 = Kb + (size_t)(kbase + r1) * 64 + c1 * 8;
    const unsigned short* vs0 = Vb + (size_t)r0 * L_ + kbase + c0 * 8;
    const unsigned short* vs1 = Vb + (size_t)r1 * L_ + kbase + c1 * 8;

    // prologue: stage staged-tile T=0 (K->Kbuf0, V->Vbuf0)
    gl_lds16(ks0, Kbuf0 + w4 * 512);
    gl_lds16(ks1, Kbuf0 + 2048 + w4 * 512);
    gl_lds16(vs0, Vbuf0 + w4 * 512);
    gl_lds16(vs1, Vbuf0 + 2048 + w4 * 512);

    // Q fragments straight to registers: B[k=d][col=q], q=q0+w4*32+l31
    const int qrow = q0 + w4 * 32 + l31;
    s16x8 qfrag[4];
#pragma unroll
    for (int ks = 0; ks < 4; ++ks)
        qfrag[ks] = ld8(Qb + (size_t)qrow * D_ + ks * 16 + hh * 8);

    // ones A-fragment for the lsum MFMA
    s16x8 onesf;
#pragma unroll
    for (int i = 0; i < 8; ++i) onesf[i] = (short)0x3F80;

    float m_ = -INFINITY;
    f32x16 lsacc = (f32x16)0.f;       // per-q key-sum accumulator (MFMA)
    f32x16 ot[2];
    ot[0] = (f32x16)0.f;
    ot[1] = (f32x16)0.f;
    s16x8 pf[2];                      // P frags of subtile s-1 (32 keys)

    const int NS = (L_ / 2) / 32;     // 32 subtiles per half (16 staged tiles)

    for (int s = 0; s < NS; ++s) {
        const int T = s >> 1;
        if ((s & 1) == 0) {
            __syncthreads();   // B1: staged tile T fully landed
            if (T + 1 < 16) {
                // K buffer (T+1)&1 dead since QK(2T-1)
                unsigned short* kn = ((T + 1) & 1) ? Kbuf1 : Kbuf0;
                gl_lds16(ks0 + (T + 1) * 4096, kn + w4 * 512);
                gl_lds16(ks1 + (T + 1) * 4096, kn + 2048 + w4 * 512);
            }
        }
        const unsigned short* __restrict__ Kl = (T & 1) ? Kbuf1 : Kbuf0;
        const int kro = (s & 1) * 32;     // key-half within staged tile

        // ---- QK(s): S^T = K·Q^T over 32 keys (log2-domain scores) ----
        f32x16 st = (f32x16)0.f;
        __builtin_amdgcn_s_setprio(1);
        {
            const int krow = kro + l31;
            const int swz = (l31 & 7) << 3;   // (krow&7)==(l31&7): kro%32==0
#pragma unroll
            for (int ks = 0; ks < 4; ++ks) {
                const s16x8 kf = ld8(&Kl[(krow * 64 + ks * 16 + hh * 8) ^ swz]);
                st = __builtin_amdgcn_mfma_f32_32x32x16_bf16(kf, qfrag[ks], st, 0, 0, 0);
            }
        }

        // ---- PV(s-1) + ones-mfma lsum (in flight during softmax(s)) ----
        if (s) {
            const unsigned short* __restrict__ Vl = (((s - 1) >> 1) & 1) ? Vbuf1 : Vbuf0;
            const int vco = ((s - 1) & 1) * 32;
#pragma unroll
            for (int dt = 0; dt < 2; ++dt) {
                const int drow = dt * 32 + l31;
                const int swz = (l31 & 7) << 3;
#pragma unroll
                for (int kc = 0; kc < 2; ++kc) {
                    const s16x8 vf = ld8(&Vl[(drow * 64 + vco + kc * 16 + hh * 8) ^ swz]);
                    ot[dt] = __builtin_amdgcn_mfma_f32_32x32x16_bf16(vf, pf[kc], ot[dt], 0, 0, 0);
                }
            }
#pragma unroll
            for (int kc = 0; kc < 2; ++kc)
                lsacc = __builtin_amdgcn_mfma_f32_32x32x16_bf16(onesf, pf[kc], lsacc, 0, 0, 0);
        }
        __builtin_amdgcn_s_setprio(0);

        if ((s & 1) == 0) {
            __syncthreads();   // B2: V(T-1) fully read by everyone
            if (T + 1 < 16) {
                unsigned short* vn = ((T + 1) & 1) ? Vbuf1 : Vbuf0;
                gl_lds16(vs0 + (T + 1) * 64, vn + w4 * 512);
                gl_lds16(vs1 + (T + 1) * 64, vn + 2048 + w4 * 512);
            }
        }

        // ---- softmax(s): 16 scores/lane; max tree + defer-max + exp + pack ----
        const float t0 = max3f(st[0],  st[1],  st[2]);
        const float t1 = max3f(st[3],  st[4],  st[5]);
        const float t2 = max3f(st[6],  st[7],  st[8]);
        const float t3 = max3f(st[9],  st[10], st[11]);
        const float t4 = max3f(st[12], st[13], st[14]);
        const float u0 = max3f(t0, t1, t2);
        const float u1 = max3f(t3, t4, st[15]);
        float tmax = fmaxf(u0, u1);
        tmax = fmaxf(tmax, __shfl_xor(tmax, 32));

        if (!__all(tmax <= m_ + 8.f)) {       // first subtile: m_=-inf -> taken
            const float newm = fmaxf(m_, tmax);
            const float corr = exp2a(m_ - newm);   // 0 on first subtile
            lsacc *= corr;
            ot[0] *= corr;
            ot[1] *= corr;
            m_ = newm;
        }

        // exp2 in place (<= 2^8 bound via defer-max)
#pragma unroll
        for (int i = 0; i < 16; ++i) st[i] = exp2a(st[i] - m_);

        // pack P -> PV B-frags (cvt_pk + permlane32_swap)
        {
            unsigned int A0 = cvtpk(st[0],  st[1]),  B0 = cvtpk(st[2],  st[3]);
            unsigned int A1 = cvtpk(st[4],  st[5]),  B1 = cvtpk(st[6],  st[7]);
            unsigned int A2 = cvtpk(st[8],  st[9]),  B2 = cvtpk(st[10], st[11]);
            unsigned int A3 = cvtpk(st[12], st[13]), B3 = cvtpk(st[14], st[15]);
            swap32(A0, A1); swap32(B0, B1);
            swap32(A2, A3); swap32(B2, B3);
            u32x4 lo; lo[0] = A0; lo[1] = B0; lo[2] = A1; lo[3] = B1;
            u32x4 hi; hi[0] = A2; hi[1] = B2; hi[2] = A3; hi[3] = B3;
            pf[0] = __builtin_bit_cast(s16x8, lo);
            pf[1] = __builtin_bit_cast(s16x8, hi);
        }
    }

    // ---- epilogue: final PV + lsum (subtile NS-1) ----
    {
        const unsigned short* __restrict__ Vl = (((NS - 1) >> 1) & 1) ? Vbuf1 : Vbuf0;
        const int vco = ((NS - 1) & 1) * 32;
        __builtin_amdgcn_s_setprio(1);
#pragma unroll
        for (int dt = 0; dt < 2; ++dt) {
            const int drow = dt * 32 + l31;
            const int swz = (l31 & 7) << 3;
#pragma unroll
            for (int kc = 0; kc < 2; ++kc) {
                const s16x8 vf = ld8(&Vl[(drow * 64 + vco + kc * 16 + hh * 8) ^ swz]);
                ot[dt] = __builtin_amdgcn_mfma_f32_32x32x16_bf16(vf, pf[kc], ot[dt], 0, 0, 0);
            }
        }
#pragma unroll
        for (int kc = 0; kc < 2; ++kc)
            lsacc = __builtin_amdgcn_mfma_f32_32x32x16_bf16(onesf, pf[kc], lsacc, 0, 0, 0);
        __builtin_amdgcn_s_setprio(0);
    }

    // ---- split-K merge via LDS (ST[0] scratch, barrier-first) ----
    __syncthreads();
    float* mrg = reinterpret_cast<float*>(&ST[0][0]);
    const int slot = ((w4 << 6) + lane) * 36;      // 36 floats/lane, 16B-aligned
    if (half == 1) {
        *reinterpret_cast<f32x16*>(&mrg[slot])      = ot[0];
        *reinterpret_cast<f32x16*>(&mrg[slot + 16]) = ot[1];
        mrg[slot + 32] = m_;
        mrg[slot + 33] = lsacc[0];
    }
    __syncthreads();
    if (half == 0) {
        const f32x16 ob0 = *reinterpret_cast<const f32x16*>(&mrg[slot]);
        const f32x16 ob1 = *reinterpret_cast<const f32x16*>(&mrg[slot + 16]);
        const float mB = mrg[slot + 32];
        const float lB = mrg[slot + 33];
        const float mm = fmaxf(m_, mB);
        const float sA = exp2a(m_ - mm);
        const float sB = exp2a(mB - mm);
        const float inv = 1.f / (lsacc[0] * sA + lB * sB);
        ot[0] = ot[0] * sA + ob0 * sB;
        ot[1] = ot[1] * sA + ob1 * sB;

#pragma unroll
        for (int dt = 0; dt < 2; ++dt) {
#pragma unroll
            for (int r = 0; r < 4; ++r) {
                uint2 o;
                o.x = cvtpk(ot[dt][4 * r + 0] * inv, ot[dt][4 * r + 1] * inv);
                o.y = cvtpk(ot[dt][4 * r + 2] * inv, ot[dt][4 * r + 3] * inv);
                const size_t elem = ((size_t)n * L_ + qrow) * E_ + h * D_ + dt * 32 + r * 8 + hh * 4;
                *reinterpret_cast<uint2*>(AO + elem) = o;
            }
        }
    }
}

// ---------------------------------------------------------------------------
// Kernel 3: output projection via bf16 MFMA with Wo = Whi + Wlo split.
// ---------------------------------------------------------------------------
__global__ __launch_bounds__(256) void out_proj_kernel(
    const unsigned short* __restrict__ AO, const unsigned short* __restrict__ Whi,
    const unsigned short* __restrict__ Wlo, const float* __restrict__ bo,
    float* __restrict__ out)
{
    __shared__ __align__(16) unsigned short Adb[2][4096];
    __shared__ __align__(16) unsigned short Hdb[2][4096];
    __shared__ __align__(16) unsigned short Ldb[2][4096];

    const int tid = threadIdx.x;
    const int bid = blockIdx.x;
    const int mt = bid >> 3, nt = bid & 7;
    const int m0 = mt * 64, n0 = nt * 64;
    const int wave = tid >> 6, lane = tid & 63;
    const int ql = lane & 15, g = lane >> 4;

    const int G0 = wave * 64 + lane;
    const int G1 = G0 + 256;
    const int r0 = G0 >> 3, c0 = (G0 & 7) ^ (r0 & 7);
    const int r1 = G1 >> 3, c1 = (G1 & 7) ^ (r1 & 7);

    const unsigned short* as0 = AO + (size_t)(m0 + r0) * E_ + c0 * 8;
    const unsigned short* as1 = AO + (size_t)(m0 + r1) * E_ + c1 * 8;
    const unsigned short* hs0 = Whi + (size_t)(n0 + r0) * E_ + c0 * 8;
    const unsigned short* hs1 = Whi + (size_t)(n0 + r1) * E_ + c1 * 8;
    const unsigned short* ls0 = Wlo + (size_t)(n0 + r0) * E_ + c0 * 8;
    const unsigned short* ls1 = Wlo + (size_t)(n0 + r1) * E_ + c1 * 8;

    gl_lds16(as0, &Adb[0][wave * 512]);
    gl_lds16(as1, &Adb[0][2048 + wave * 512]);
    gl_lds16(hs0, &Hdb[0][wave * 512]);
    gl_lds16(hs1, &Hdb[0][2048 + wave * 512]);
    gl_lds16(ls0, &Ldb[0][wave * 512]);
    gl_lds16(ls1, &Ldb[0][2048 + wave * 512]);

    float bias[4];
#pragma unroll
    for (int t = 0; t < 4; ++t) bias[t] = bo[n0 + t * 16 + ql];

    f32x4 acc[4];
#pragma unroll
    for (int t = 0; t < 4; ++t) acc[t] = (f32x4){0.f, 0.f, 0.f, 0.f};

    const int arow = wave * 16 + ql;

    for (int kc = 0; kc < 8; ++kc) {
        const int b = kc & 1;
        __syncthreads();
        if (kc + 1 < 8) {
            const int nb = b ^ 1;
            const int ko = (kc + 1) * 64;
            gl_lds16(as0 + ko, &Adb[nb][wave * 512]);
            gl_lds16(as1 + ko, &Adb[nb][2048 + wave * 512]);
            gl_lds16(hs0 + ko, &Hdb[nb][wave * 512]);
            gl_lds16(hs1 + ko, &Hdb[nb][2048 + wave * 512]);
            gl_lds16(ls0 + ko, &Ldb[nb][wave * 512]);
            gl_lds16(ls1 + ko, &Ldb[nb][2048 + wave * 512]);
        }
        const unsigned short* __restrict__ Al = Adb[b];
        const unsigned short* __restrict__ Hl = Hdb[b];
        const unsigned short* __restrict__ Ll = Ldb[b];

        s16x8 af[2];
#pragma unroll
        for (int ks = 0; ks < 2; ++ks)
            af[ks] = ld8(&Al[(arow * 64 + ks * 32 + g * 8) ^ ((arow & 7) << 3)]);

        __builtin_amdgcn_s_setprio(1);
#pragma unroll
        for (int t = 0; t < 4; ++t) {
            const int wrow = t * 16 + ql;
#pragma unroll
            for (int ks = 0; ks < 2; ++ks) {
                const s16x8 bh = ld8(&Hl[(wrow * 64 + ks * 32 + g * 8) ^ ((wrow & 7) << 3)]);
                acc[t] = __builtin_amdgcn_mfma_f32_16x16x32_bf16(af[ks], bh, acc[t], 0, 0, 0);
                const s16x8 bl = ld8(&Ll[(wrow * 64 + ks * 32 + g * 8) ^ ((wrow & 7) << 3)]);
                acc[t] = __builtin_amdgcn_mfma_f32_16x16x32_bf16(af[ks], bl, acc[t], 0, 0, 0);
            }
        }
        __builtin_amdgcn_s_setprio(0);
    }

    // epilogue: D[m = m0+wave*16+g*4+r][n = n0+t*16+ql]
#pragma unroll
    for (int t = 0; t < 4; ++t) {
#pragma unroll
        for (int r = 0; r < 4; ++r) {
            out[(size_t)(m0 + wave * 16 + g * 4 + r) * E_ + n0 + t * 16 + ql] =
                acc[t][r] + bias[t];
        }
    }
}

// ---------------------------------------------------------------------------
extern "C" void kernel_launch(void* const* d_in, const int* in_sizes, int n_in,
                              void* d_out, int out_size, void* d_ws, size_t ws_size,
                              hipStream_t stream)
{
    const float* Q  = (const float*)d_in[0];
    const float* K  = (const float*)d_in[1];
    const float* V  = (const float*)d_in[2];
    const float* Wq = (const float*)d_in[3];
    const float* Wk = (const float*)d_in[4];
    const float* Wv = (const float*)d_in[5];
    const float* Wo = (const float*)d_in[6];
    const float* bo = (const float*)d_in[7];
    float* out = (float*)d_out;

    unsigned short* ws = (unsigned short*)d_ws;
    const size_t SZ = (size_t)N_ * H_ * L_ * D_;   // 4,194,304 elems
    unsigned short* Qp  = ws;
    unsigned short* Kp  = ws + SZ;
    unsigned short* Vt  = ws + 2 * SZ;
    unsigned short* AO  = ws + 3 * SZ;
    unsigned short* Whi = ws + 4 * SZ;
    unsigned short* Wlo = ws + 4 * SZ + 262144;

    qkv_proj_kernel<<<dim3(32, 32, 4), 256, 0, stream>>>(Q, K, V, Wq, Wk, Wv, Wo,
                                                         Qp, Kp, Vt, Whi, Wlo);
    attn_kernel<<<512, 512, 0, stream>>>(Qp, Kp, Vt, AO);
    out_proj_kernel<<<(8192 / 64) * (E_ / 64), 256, 0, stream>>>(AO, Whi, Wlo, bo, out);
}

// Round 17
// 86.773 us; speedup vs baseline: 1.7964x; 1.0267x over previous
//
#include <hip/hip_runtime.h>
#include <math.h>

#define N_ 4
#define L_ 2048
#define E_ 512
#define H_ 8
#define D_ 64

// SCALE = 1/sqrt(512) (reference scales by sqrt(embed_size));
// QSCALE = SCALE * log2(e): scores come out of QK^T in log2 domain.
#define QSCALE 0.06375871588055019f

typedef short s16x8 __attribute__((ext_vector_type(8)));
typedef float f32x4 __attribute__((ext_vector_type(4)));
typedef float f32x16 __attribute__((ext_vector_type(16)));
typedef unsigned int u32x4 __attribute__((ext_vector_type(4)));

typedef const __attribute__((address_space(1))) unsigned int ga_u32;
typedef __attribute__((address_space(3))) unsigned int lds_u32;

// async 16B global->LDS (dest = wave-uniform base + lane*16, linear)
__device__ __forceinline__ void gl_lds16(const unsigned short* g, unsigned short* l) {
    __builtin_amdgcn_global_load_lds((ga_u32*)g, (lds_u32*)l, 16, 0, 0);
}
__device__ __forceinline__ float exp2a(float x) {
    float r; asm("v_exp_f32 %0, %1" : "=v"(r) : "v"(x)); return r;
}
__device__ __forceinline__ unsigned int cvtpk(float lo, float hi) {
    unsigned int r; asm("v_cvt_pk_bf16_f32 %0, %1, %2" : "=v"(r) : "v"(lo), "v"(hi)); return r;
}
// v_permlane32_swap_b32 a, b: a<-{a_lo, b_lo}, b<-{a_hi, b_hi} (lane halves)
__device__ __forceinline__ void swap32(unsigned int& a, unsigned int& b) {
    asm volatile("v_permlane32_swap_b32 %0, %1" : "+v"(a), "+v"(b));
}
__device__ __forceinline__ float max3f(float a, float b, float c) {
    return fmaxf(fmaxf(a, b), c);   // clang fuses to v_max3_f32
}
__device__ __forceinline__ unsigned short f2bf(float x) {
    unsigned int u = __builtin_bit_cast(unsigned int, x);
    u = (u + 0x7FFFu + ((u >> 16) & 1u)) >> 16;   // RNE
    return (unsigned short)u;
}
__device__ __forceinline__ float bflo(unsigned int w) {
    return __builtin_bit_cast(float, w << 16);
}
__device__ __forceinline__ float bfhi(unsigned int w) {
    return __builtin_bit_cast(float, w & 0xFFFF0000u);
}
__device__ __forceinline__ s16x8 ld8(const unsigned short* p) {
    return *reinterpret_cast<const s16x8*>(p);
}

// ---------------------------------------------------------------------------
// Kernel 1: per-head QKV projection via bf16 MFMA (round-12 verified).
// z-slice m==3 (first 256 blocks): wo_split folded in (saves a dispatch).
// ---------------------------------------------------------------------------
__global__ __launch_bounds__(256) void qkv_proj_kernel(
    const float* __restrict__ Q, const float* __restrict__ K, const float* __restrict__ V,
    const float* __restrict__ Wq, const float* __restrict__ Wk, const float* __restrict__ Wv,
    const float* __restrict__ Wo,
    unsigned short* __restrict__ Qp, unsigned short* __restrict__ Kp,
    unsigned short* __restrict__ Vt,
    unsigned short* __restrict__ Whi, unsigned short* __restrict__ Wlo)
{
    __shared__ __align__(16) unsigned short Xl[4096];     // bf16, swizzled
    __shared__ __align__(16) unsigned short Whl[4096];    // W hi, swizzled
    __shared__ __align__(16) unsigned short Wll[4096];    // W lo, swizzled
    __shared__ __align__(16) unsigned short Yl[64][72];

    const int tid = threadIdx.x;
    const int lt = blockIdx.x;
    const int nh = blockIdx.y;
    const int m  = blockIdx.z;       // 0:Q 1:K 2:V 3:wo_split
    const int n = nh >> 3, h = nh & 7;
    const int l0 = lt * 64;

    if (m == 3) {
        const int bidx = lt + nh * 32;
        if (bidx < 256) {
            const int i = bidx * 256 + tid;
            const float4 w = reinterpret_cast<const float4*>(Wo)[i];
            const unsigned int hxy = cvtpk(w.x, w.y);
            const unsigned int hzw = cvtpk(w.z, w.w);
            const unsigned int lxy = cvtpk(w.x - bflo(hxy), w.y - bfhi(hxy));
            const unsigned int lzw = cvtpk(w.z - bflo(hzw), w.w - bfhi(hzw));
            uint2 hh2; hh2.x = hxy; hh2.y = hzw;
            uint2 ll2; ll2.x = lxy; ll2.y = lzw;
            reinterpret_cast<uint2*>(Whi)[i] = hh2;
            reinterpret_cast<uint2*>(Wlo)[i] = ll2;
        }
        return;
    }

    const float* __restrict__ in = (m == 0) ? Q : (m == 1) ? K : V;
    const float* __restrict__ W  = (m == 0) ? Wq : (m == 1) ? Wk : Wv;

    const int xr = tid >> 2;              // 0..63
    const int xc = (tid & 3) * 16;        // col base
    {
        const float* xs = in + (size_t)(n * L_ + l0 + xr) * E_ + h * D_ + xc;
        float4 a = reinterpret_cast<const float4*>(xs)[0];
        float4 b = reinterpret_cast<const float4*>(xs)[1];
        float4 c = reinterpret_cast<const float4*>(xs)[2];
        float4 d = reinterpret_cast<const float4*>(xs)[3];
        u32x4 w0, w1;
        w0[0] = cvtpk(a.x, a.y); w0[1] = cvtpk(a.z, a.w);
        w0[2] = cvtpk(b.x, b.y); w0[3] = cvtpk(b.z, b.w);
        w1[0] = cvtpk(c.x, c.y); w1[1] = cvtpk(c.z, c.w);
        w1[2] = cvtpk(d.x, d.y); w1[3] = cvtpk(d.z, d.w);
        const int base  = (xr * 64 + xc) ^ ((xr & 7) << 3);
        const int base2 = (xr * 64 + xc + 8) ^ ((xr & 7) << 3);
        *reinterpret_cast<u32x4*>(&Xl[base])  = w0;
        *reinterpret_cast<u32x4*>(&Xl[base2]) = w1;

        const float* wsrc = W + (size_t)xr * D_ + xc;
        float wv[16];
#pragma unroll
        for (int i = 0; i < 4; ++i) {
            const float4 t = reinterpret_cast<const float4*>(wsrc)[i];
            wv[i * 4 + 0] = t.x; wv[i * 4 + 1] = t.y;
            wv[i * 4 + 2] = t.z; wv[i * 4 + 3] = t.w;
        }
        if (m == 0) {
#pragma unroll
            for (int i = 0; i < 16; ++i) wv[i] *= QSCALE;
        }
        u32x4 hi0, hi1, lo0, lo1;
#pragma unroll
        for (int i = 0; i < 4; ++i) {
            const unsigned int hw = cvtpk(wv[2 * i], wv[2 * i + 1]);
            hi0[i] = hw;
            lo0[i] = cvtpk(wv[2 * i] - bflo(hw), wv[2 * i + 1] - bfhi(hw));
        }
#pragma unroll
        for (int i = 0; i < 4; ++i) {
            const unsigned int hw = cvtpk(wv[8 + 2 * i], wv[8 + 2 * i + 1]);
            hi1[i] = hw;
            lo1[i] = cvtpk(wv[8 + 2 * i] - bflo(hw), wv[8 + 2 * i + 1] - bfhi(hw));
        }
        *reinterpret_cast<u32x4*>(&Whl[base])  = hi0;
        *reinterpret_cast<u32x4*>(&Whl[base2]) = hi1;
        *reinterpret_cast<u32x4*>(&Wll[base])  = lo0;
        *reinterpret_cast<u32x4*>(&Wll[base2]) = lo1;
    }
    __syncthreads();

    const int wave = tid >> 6, lane = tid & 63;
    const int ql = lane & 15, g = lane >> 4;
    const int arow = wave * 16 + ql;

    f32x4 acc[4];
#pragma unroll
    for (int t = 0; t < 4; ++t) acc[t] = (f32x4){0.f, 0.f, 0.f, 0.f};

    if (m < 2) {
        s16x8 xf[2];
#pragma unroll
        for (int ks = 0; ks < 2; ++ks)
            xf[ks] = ld8(&Xl[(arow * 64 + ks * 32 + g * 8) ^ ((arow & 7) << 3)]);
#pragma unroll
        for (int t = 0; t < 4; ++t) {
            const int wrow = t * 16 + ql;
#pragma unroll
            for (int ks = 0; ks < 2; ++ks) {
                const s16x8 bh = ld8(&Whl[(wrow * 64 + ks * 32 + g * 8) ^ ((wrow & 7) << 3)]);
                acc[t] = __builtin_amdgcn_mfma_f32_16x16x32_bf16(xf[ks], bh, acc[t], 0, 0, 0);
                const s16x8 bl = ld8(&Wll[(wrow * 64 + ks * 32 + g * 8) ^ ((wrow & 7) << 3)]);
                acc[t] = __builtin_amdgcn_mfma_f32_16x16x32_bf16(xf[ks], bl, acc[t], 0, 0, 0);
            }
        }
    } else {
        s16x8 whf[2], wlf[2];
#pragma unroll
        for (int ks = 0; ks < 2; ++ks) {
            whf[ks] = ld8(&Whl[(arow * 64 + ks * 32 + g * 8) ^ ((arow & 7) << 3)]);
            wlf[ks] = ld8(&Wll[(arow * 64 + ks * 32 + g * 8) ^ ((arow & 7) << 3)]);
        }
#pragma unroll
        for (int t = 0; t < 4; ++t) {
            const int xrow = t * 16 + ql;
#pragma unroll
            for (int ks = 0; ks < 2; ++ks) {
                const s16x8 bx = ld8(&Xl[(xrow * 64 + ks * 32 + g * 8) ^ ((xrow & 7) << 3)]);
                acc[t] = __builtin_amdgcn_mfma_f32_16x16x32_bf16(whf[ks], bx, acc[t], 0, 0, 0);
                acc[t] = __builtin_amdgcn_mfma_f32_16x16x32_bf16(wlf[ks], bx, acc[t], 0, 0, 0);
            }
        }
    }

#pragma unroll
    for (int t = 0; t < 4; ++t)
#pragma unroll
        for (int r = 0; r < 4; ++r)
            Yl[wave * 16 + g * 4 + r][t * 16 + ql] = f2bf(acc[t][r]);
    __syncthreads();

    const int orow = tid >> 2;
    const int oc = (tid & 3) * 16;
    const uint4 v0 = *reinterpret_cast<const uint4*>(&Yl[orow][oc]);
    const uint4 v1 = *reinterpret_cast<const uint4*>(&Yl[orow][oc + 8]);
    unsigned short* dst;
    if (m == 0)      dst = Qp + ((size_t)nh * L_ + l0 + orow) * D_ + oc;
    else if (m == 1) dst = Kp + ((size_t)nh * L_ + l0 + orow) * D_ + oc;
    else             dst = Vt + ((size_t)nh * D_ + orow) * L_ + l0 + oc;
    *reinterpret_cast<uint4*>(dst) = v0;
    *reinterpret_cast<uint4*>(dst + 8) = v1;
}

// ---------------------------------------------------------------------------
// Kernel 2: bf16 MFMA flash attention, 32x32x16, in-block split-K, 64KB LDS,
// 32-key compute subtiles + ones-MFMA lsum (round-16 verified).
// ---------------------------------------------------------------------------
__global__ __launch_bounds__(512, 2) void attn_kernel(
    const unsigned short* __restrict__ Qp, const unsigned short* __restrict__ Kp,
    const unsigned short* __restrict__ Vt, unsigned short* __restrict__ AO)
{
    // [half][buf]: 0-1 = K double-buffer, 2-3 = V double-buffer (64KB total)
    __shared__ __align__(16) unsigned short ST[2][4 * 4096];

    const int tid = threadIdx.x;
    const int phys = blockIdx.x;
    const int bid = (phys & 7) * 64 + (phys >> 3);   // bijective: 512 = 8*64
    const int qt = bid & 15;
    const int nh = bid >> 4;          // 4 heads per XCD -> K/V L2-resident
    const int n = nh >> 3, h = nh & 7;
    const int q0 = qt * 128;
    const int wave = tid >> 6;
    const int half = wave >> 2;       // key-range half
    const int w4 = wave & 3;          // wave-in-half: owns q rows w4*32..+31
    const int lane = tid & 63;
    const int l31 = lane & 31;
    const int hh  = lane >> 5;

    const unsigned short* __restrict__ Qb = Qp + (size_t)nh * (L_ * D_);
    const unsigned short* __restrict__ Kb = Kp + (size_t)nh * (L_ * D_);
    const unsigned short* __restrict__ Vb = Vt + (size_t)nh * (D_ * L_);

    unsigned short* const Kbuf0 = &ST[half][0];
    unsigned short* const Kbuf1 = &ST[half][4096];
    unsigned short* const Vbuf0 = &ST[half][2 * 4096];
    unsigned short* const Vbuf1 = &ST[half][3 * 4096];

    // staging geometry: granule G -> global (row=G>>3, c8=(G&7)^(row&7))
    const int G0 = w4 * 64 + lane;
    const int G1 = G0 + 256;
    const int r0 = G0 >> 3, c0 = (G0 & 7) ^ (r0 & 7);
    const int r1 = G1 >> 3, c1 = (G1 & 7) ^ (r1 & 7);

    const int kbase = half * 1024;    // first key of this half
    const unsigned short* ks0 = Kb + (size_t)(kbase + r0) * 64 + c0 * 8;
    const unsigned short* ks1 = Kb + (size_t)(kbase + r1) * 64 + c1 * 8;
    const unsigned short* vs0 = Vb + (size_t)r0 * L_ + kbase + c0 * 8;
    const unsigned short* vs1 = Vb + (size_t)r1 * L_ + kbase + c1 * 8;

    // prologue: stage staged-tile T=0 (K->Kbuf0, V->Vbuf0)
    gl_lds16(ks0, Kbuf0 + w4 * 512);
    gl_lds16(ks1, Kbuf0 + 2048 + w4 * 512);
    gl_lds16(vs0, Vbuf0 + w4 * 512);
    gl_lds16(vs1, Vbuf0 + 2048 + w4 * 512);

    // Q fragments straight to registers: B[k=d][col=q], q=q0+w4*32+l31
    const int qrow = q0 + w4 * 32 + l31;
    s16x8 qfrag[4];
#pragma unroll
    for (int ks = 0; ks < 4; ++ks)
        qfrag[ks] = ld8(Qb + (size_t)qrow * D_ + ks * 16 + hh * 8);

    // ones A-fragment for the lsum MFMA
    s16x8 onesf;
#pragma unroll
    for (int i = 0; i < 8; ++i) onesf[i] = (short)0x3F80;

    float m_ = -INFINITY;
    f32x16 lsacc = (f32x16)0.f;       // per-q key-sum accumulator (MFMA)
    f32x16 ot[2];
    ot[0] = (f32x16)0.f;
    ot[1] = (f32x16)0.f;
    s16x8 pf[2];                      // P frags of subtile s-1 (32 keys)

    const int NS = (L_ / 2) / 32;     // 32 subtiles per half (16 staged tiles)

    for (int s = 0; s < NS; ++s) {
        const int T = s >> 1;
        if ((s & 1) == 0) {
            __syncthreads();   // B1: staged tile T fully landed
            if (T + 1 < 16) {
                // K buffer (T+1)&1 dead since QK(2T-1)
                unsigned short* kn = ((T + 1) & 1) ? Kbuf1 : Kbuf0;
                gl_lds16(ks0 + (T + 1) * 4096, kn + w4 * 512);
                gl_lds16(ks1 + (T + 1) * 4096, kn + 2048 + w4 * 512);
            }
        }
        const unsigned short* __restrict__ Kl = (T & 1) ? Kbuf1 : Kbuf0;
        const int kro = (s & 1) * 32;     // key-half within staged tile

        // ---- QK(s): S^T = K·Q^T over 32 keys (log2-domain scores) ----
        f32x16 st = (f32x16)0.f;
        __builtin_amdgcn_s_setprio(1);
        {
            const int krow = kro + l31;
            const int swz = (l31 & 7) << 3;   // (krow&7)==(l31&7): kro%32==0
#pragma unroll
            for (int ks = 0; ks < 4; ++ks) {
                const s16x8 kf = ld8(&Kl[(krow * 64 + ks * 16 + hh * 8) ^ swz]);
                st = __builtin_amdgcn_mfma_f32_32x32x16_bf16(kf, qfrag[ks], st, 0, 0, 0);
            }
        }

        // ---- PV(s-1) + ones-mfma lsum (in flight during softmax(s)) ----
        if (s) {
            const unsigned short* __restrict__ Vl = (((s - 1) >> 1) & 1) ? Vbuf1 : Vbuf0;
            const int vco = ((s - 1) & 1) * 32;
#pragma unroll
            for (int dt = 0; dt < 2; ++dt) {
                const int drow = dt * 32 + l31;
                const int swz = (l31 & 7) << 3;
#pragma unroll
                for (int kc = 0; kc < 2; ++kc) {
                    const s16x8 vf = ld8(&Vl[(drow * 64 + vco + kc * 16 + hh * 8) ^ swz]);
                    ot[dt] = __builtin_amdgcn_mfma_f32_32x32x16_bf16(vf, pf[kc], ot[dt], 0, 0, 0);
                }
            }
#pragma unroll
            for (int kc = 0; kc < 2; ++kc)
                lsacc = __builtin_amdgcn_mfma_f32_32x32x16_bf16(onesf, pf[kc], lsacc, 0, 0, 0);
        }
        __builtin_amdgcn_s_setprio(0);

        if ((s & 1) == 0) {
            __syncthreads();   // B2: V(T-1) fully read by everyone
            if (T + 1 < 16) {
                unsigned short* vn = ((T + 1) & 1) ? Vbuf1 : Vbuf0;
                gl_lds16(vs0 + (T + 1) * 64, vn + w4 * 512);
                gl_lds16(vs1 + (T + 1) * 64, vn + 2048 + w4 * 512);
            }
        }

        // ---- softmax(s): 16 scores/lane; max tree + defer-max + exp + pack ----
        const float t0 = max3f(st[0],  st[1],  st[2]);
        const float t1 = max3f(st[3],  st[4],  st[5]);
        const float t2 = max3f(st[6],  st[7],  st[8]);
        const float t3 = max3f(st[9],  st[10], st[11]);
        const float t4 = max3f(st[12], st[13], st[14]);
        const float u0 = max3f(t0, t1, t2);
        const float u1 = max3f(t3, t4, st[15]);
        float tmax = fmaxf(u0, u1);
        tmax = fmaxf(tmax, __shfl_xor(tmax, 32));

        if (!__all(tmax <= m_ + 8.f)) {       // first subtile: m_=-inf -> taken
            const float newm = fmaxf(m_, tmax);
            const float corr = exp2a(m_ - newm);   // 0 on first subtile
            lsacc *= corr;
            ot[0] *= corr;
            ot[1] *= corr;
            m_ = newm;
        }

        // exp2 in place (<= 2^8 bound via defer-max)
#pragma unroll
        for (int i = 0; i < 16; ++i) st[i] = exp2a(st[i] - m_);

        // pack P -> PV B-frags (cvt_pk + permlane32_swap)
        {
            unsigned int A0 = cvtpk(st[0],  st[1]),  B0 = cvtpk(st[2],  st[3]);
            unsigned int A1 = cvtpk(st[4],  st[5]),  B1 = cvtpk(st[6],  st[7]);
            unsigned int A2 = cvtpk(st[8],  st[9]),  B2 = cvtpk(st[10], st[11]);
            unsigned int A3 = cvtpk(st[12], st[13]), B3 = cvtpk(st[14], st[15]);
            swap32(A0, A1); swap32(B0, B1);
            swap32(A2, A3); swap32(B2, B3);
            u32x4 lo; lo[0] = A0; lo[1] = B0; lo[2] = A1; lo[3] = B1;
            u32x4 hi; hi[0] = A2; hi[1] = B2; hi[2] = A3; hi[3] = B3;
            pf[0] = __builtin_bit_cast(s16x8, lo);
            pf[1] = __builtin_bit_cast(s16x8, hi);
        }
    }

    // ---- epilogue: final PV + lsum (subtile NS-1) ----
    {
        const unsigned short* __restrict__ Vl = (((NS - 1) >> 1) & 1) ? Vbuf1 : Vbuf0;
        const int vco = ((NS - 1) & 1) * 32;
        __builtin_amdgcn_s_setprio(1);
#pragma unroll
        for (int dt = 0; dt < 2; ++dt) {
            const int drow = dt * 32 + l31;
            const int swz = (l31 & 7) << 3;
#pragma unroll
            for (int kc = 0; kc < 2; ++kc) {
                const s16x8 vf = ld8(&Vl[(drow * 64 + vco + kc * 16 + hh * 8) ^ swz]);
                ot[dt] = __builtin_amdgcn_mfma_f32_32x32x16_bf16(vf, pf[kc], ot[dt], 0, 0, 0);
            }
        }
#pragma unroll
        for (int kc = 0; kc < 2; ++kc)
            lsacc = __builtin_amdgcn_mfma_f32_32x32x16_bf16(onesf, pf[kc], lsacc, 0, 0, 0);
        __builtin_amdgcn_s_setprio(0);
    }

    // ---- split-K merge via LDS (ST[0] scratch, barrier-first) ----
    __syncthreads();
    float* mrg = reinterpret_cast<float*>(&ST[0][0]);
    const int slot = ((w4 << 6) + lane) * 36;      // 36 floats/lane, 16B-aligned
    if (half == 1) {
        *reinterpret_cast<f32x16*>(&mrg[slot])      = ot[0];
        *reinterpret_cast<f32x16*>(&mrg[slot + 16]) = ot[1];
        mrg[slot + 32] = m_;
        mrg[slot + 33] = lsacc[0];
    }
    __syncthreads();
    if (half == 0) {
        const f32x16 ob0 = *reinterpret_cast<const f32x16*>(&mrg[slot]);
        const f32x16 ob1 = *reinterpret_cast<const f32x16*>(&mrg[slot + 16]);
        const float mB = mrg[slot + 32];
        const float lB = mrg[slot + 33];
        const float mm = fmaxf(m_, mB);
        const float sA = exp2a(m_ - mm);
        const float sB = exp2a(mB - mm);
        const float inv = 1.f / (lsacc[0] * sA + lB * sB);
        ot[0] = ot[0] * sA + ob0 * sB;
        ot[1] = ot[1] * sA + ob1 * sB;

#pragma unroll
        for (int dt = 0; dt < 2; ++dt) {
#pragma unroll
            for (int r = 0; r < 4; ++r) {
                uint2 o;
                o.x = cvtpk(ot[dt][4 * r + 0] * inv, ot[dt][4 * r + 1] * inv);
                o.y = cvtpk(ot[dt][4 * r + 2] * inv, ot[dt][4 * r + 3] * inv);
                const size_t elem = ((size_t)n * L_ + qrow) * E_ + h * D_ + dt * 32 + r * 8 + hh * 4;
                *reinterpret_cast<uint2*>(AO + elem) = o;
            }
        }
    }
}

// ---------------------------------------------------------------------------
// Kernel 3: output projection via bf16 MFMA, Wo = Whi + Wlo split.
// THIS ROUND: 64x128 output tile per block (512 blocks = 128m x 4n) -> 32
// MFMA per wave between barrier pairs (2x amortization of the vmcnt-drain
// barrier), A re-reads halved. W granule trick: granule G+512 has row+64,
// same (row&7) -> same swizzle column as G. LDS 80KB -> 2 blocks/CU.
// ---------------------------------------------------------------------------
__global__ __launch_bounds__(256) void out_proj_kernel(
    const unsigned short* __restrict__ AO, const unsigned short* __restrict__ Whi,
    const unsigned short* __restrict__ Wlo, const float* __restrict__ bo,
    float* __restrict__ out)
{
    __shared__ __align__(16) unsigned short Adb[2][4096];    // 64x64 bf16
    __shared__ __align__(16) unsigned short Hdb[2][8192];    // 128x64 bf16
    __shared__ __align__(16) unsigned short Ldb[2][8192];    // 128x64 bf16

    const int tid = threadIdx.x;
    const int bid = blockIdx.x;
    const int mt = bid >> 2, nt = bid & 3;
    const int m0 = mt * 64, n0 = nt * 128;
    const int wave = tid >> 6, lane = tid & 63;
    const int ql = lane & 15, g = lane >> 4;

    const int G0 = wave * 64 + lane;
    const int G1 = G0 + 256;
    const int r0 = G0 >> 3, c0 = (G0 & 7) ^ (r0 & 7);
    const int r1 = G1 >> 3, c1 = (G1 & 7) ^ (r1 & 7);
    // W granules G0+512, G1+512: rows r0+64, r1+64; same swizzle cols c0, c1.

    const unsigned short* as0 = AO + (size_t)(m0 + r0) * E_ + c0 * 8;
    const unsigned short* as1 = AO + (size_t)(m0 + r1) * E_ + c1 * 8;
    const unsigned short* hs0 = Whi + (size_t)(n0 + r0) * E_ + c0 * 8;
    const unsigned short* hs1 = Whi + (size_t)(n0 + r1) * E_ + c1 * 8;
    const unsigned short* hs2 = Whi + (size_t)(n0 + r0 + 64) * E_ + c0 * 8;
    const unsigned short* hs3 = Whi + (size_t)(n0 + r1 + 64) * E_ + c1 * 8;
    const unsigned short* ls0 = Wlo + (size_t)(n0 + r0) * E_ + c0 * 8;
    const unsigned short* ls1 = Wlo + (size_t)(n0 + r1) * E_ + c1 * 8;
    const unsigned short* ls2 = Wlo + (size_t)(n0 + r0 + 64) * E_ + c0 * 8;
    const unsigned short* ls3 = Wlo + (size_t)(n0 + r1 + 64) * E_ + c1 * 8;

    gl_lds16(as0, &Adb[0][wave * 512]);
    gl_lds16(as1, &Adb[0][2048 + wave * 512]);
    gl_lds16(hs0, &Hdb[0][wave * 512]);
    gl_lds16(hs1, &Hdb[0][2048 + wave * 512]);
    gl_lds16(hs2, &Hdb[0][4096 + wave * 512]);
    gl_lds16(hs3, &Hdb[0][6144 + wave * 512]);
    gl_lds16(ls0, &Ldb[0][wave * 512]);
    gl_lds16(ls1, &Ldb[0][2048 + wave * 512]);
    gl_lds16(ls2, &Ldb[0][4096 + wave * 512]);
    gl_lds16(ls3, &Ldb[0][6144 + wave * 512]);

    float bias[8];
#pragma unroll
    for (int t = 0; t < 8; ++t) bias[t] = bo[n0 + t * 16 + ql];

    f32x4 acc[8];
#pragma unroll
    for (int t = 0; t < 8; ++t) acc[t] = (f32x4){0.f, 0.f, 0.f, 0.f};

    const int arow = wave * 16 + ql;

    for (int kc = 0; kc < 8; ++kc) {
        const int b = kc & 1;
        __syncthreads();
        if (kc + 1 < 8) {
            const int nb = b ^ 1;
            const int ko = (kc + 1) * 64;
            gl_lds16(as0 + ko, &Adb[nb][wave * 512]);
            gl_lds16(as1 + ko, &Adb[nb][2048 + wave * 512]);
            gl_lds16(hs0 + ko, &Hdb[nb][wave * 512]);
            gl_lds16(hs1 + ko, &Hdb[nb][2048 + wave * 512]);
            gl_lds16(hs2 + ko, &Hdb[nb][4096 + wave * 512]);
            gl_lds16(hs3 + ko, &Hdb[nb][6144 + wave * 512]);
            gl_lds16(ls0 + ko, &Ldb[nb][wave * 512]);
            gl_lds16(ls1 + ko, &Ldb[nb][2048 + wave * 512]);
            gl_lds16(ls2 + ko, &Ldb[nb][4096 + wave * 512]);
            gl_lds16(ls3 + ko, &Ldb[nb][6144 + wave * 512]);
        }
        const unsigned short* __restrict__ Al = Adb[b];
        const unsigned short* __restrict__ Hl = Hdb[b];
        const unsigned short* __restrict__ Ll = Ldb[b];

        s16x8 af[2];
#pragma unroll
        for (int ks = 0; ks < 2; ++ks)
            af[ks] = ld8(&Al[(arow * 64 + ks * 32 + g * 8) ^ ((arow & 7) << 3)]);

        __builtin_amdgcn_s_setprio(1);
#pragma unroll
        for (int t = 0; t < 8; ++t) {
            const int wrow = t * 16 + ql;
#pragma unroll
            for (int ks = 0; ks < 2; ++ks) {
                const s16x8 bh = ld8(&Hl[(wrow * 64 + ks * 32 + g * 8) ^ ((wrow & 7) << 3)]);
                acc[t] = __builtin_amdgcn_mfma_f32_16x16x32_bf16(af[ks], bh, acc[t], 0, 0, 0);
                const s16x8 bl = ld8(&Ll[(wrow * 64 + ks * 32 + g * 8) ^ ((wrow & 7) << 3)]);
                acc[t] = __builtin_amdgcn_mfma_f32_16x16x32_bf16(af[ks], bl, acc[t], 0, 0, 0);
            }
        }
        __builtin_amdgcn_s_setprio(0);
    }

    // epilogue: D[m = m0+wave*16+g*4+r][n = n0+t*16+ql]
#pragma unroll
    for (int t = 0; t < 8; ++t) {
#pragma unroll
        for (int r = 0; r < 4; ++r) {
            out[(size_t)(m0 + wave * 16 + g * 4 + r) * E_ + n0 + t * 16 + ql] =
                acc[t][r] + bias[t];
        }
    }
}

// ---------------------------------------------------------------------------
extern "C" void kernel_launch(void* const* d_in, const int* in_sizes, int n_in,
                              void* d_out, int out_size, void* d_ws, size_t ws_size,
                              hipStream_t stream)
{
    const float* Q  = (const float*)d_in[0];
    const float* K  = (const float*)d_in[1];
    const float* V  = (const float*)d_in[2];
    const float* Wq = (const float*)d_in[3];
    const float* Wk = (const float*)d_in[4];
    const float* Wv = (const float*)d_in[5];
    const float* Wo = (const float*)d_in[6];
    const float* bo = (const float*)d_in[7];
    float* out = (float*)d_out;

    unsigned short* ws = (unsigned short*)d_ws;
    const size_t SZ = (size_t)N_ * H_ * L_ * D_;   // 4,194,304 elems
    unsigned short* Qp  = ws;
    unsigned short* Kp  = ws + SZ;
    unsigned short* Vt  = ws + 2 * SZ;
    unsigned short* AO  = ws + 3 * SZ;
    unsigned short* Whi = ws + 4 * SZ;
    unsigned short* Wlo = ws + 4 * SZ + 262144;

    qkv_proj_kernel<<<dim3(32, 32, 4), 256, 0, stream>>>(Q, K, V, Wq, Wk, Wv, Wo,
                                                         Qp, Kp, Vt, Whi, Wlo);
    attn_kernel<<<512, 512, 0, stream>>>(Qp, Kp, Vt, AO);
    out_proj_kernel<<<(8192 / 64) * (E_ / 128), 256, 0, stream>>>(AO, Whi, Wlo, bo, out);
}